// Round 4
// baseline (336.028 us; speedup 1.0000x reference)
//
#include <hip/hip_runtime.h>

#define T_TOK  2048
#define DIMD   1024
#define INTERI 512
#define NEXP   16
#define NSEG   17   // 16 routed + 1 shared (index 16)

typedef __bf16 bf16x8 __attribute__((ext_vector_type(8)));
typedef float  f32x4  __attribute__((ext_vector_type(4)));
typedef float  f32x8  __attribute__((ext_vector_type(8)));

// XOR-swizzle: chunk c (8 elems) of row r lives at slot (c + (r>>1)) & 3.
// Makes b128 reads (lrow=lane&15 varying) conflict-free per quarter-wave.
#define SW(row, c) ((((c) + ((row) >> 1)) & 3) * 8)

// ---------- helpers ----------
__device__ __forceinline__ unsigned short f2b(float f) {
    union { float f; unsigned int u; } c; c.f = f;
    unsigned int u = c.u;
    unsigned int r = (u + 0x7FFFu + ((u >> 16) & 1u)) >> 16;  // RNE
    return (unsigned short)r;
}

// fp32x8 -> bf16x8 (RNE via v_cvt_pk_bf16_f32)
__device__ __forceinline__ bf16x8 cvt8(f32x8 v) {
    bf16x8 r;
#pragma unroll
    for (int i = 0; i < 8; ++i) r[i] = (__bf16)v[i];
    return r;
}

// raw barrier: waits only LDS ops, leaves global loads in flight
__device__ __forceinline__ void lds_barrier() {
    asm volatile("s_waitcnt lgkmcnt(0)" ::: "memory");
    __builtin_amdgcn_s_barrier();
}

// ---------- prep: weight cvt + gate (+ atomic list build), ONE launch ----------
// blocks [0,8704): cvt w1/w3/ws1/ws3 (8 floats/thread)
// blocks [8704,9216): gate (one wave per token) + x->bf16 + list build
__global__ __launch_bounds__(256) void prep_kernel(
    const float* __restrict__ w1,  const float* __restrict__ w3,
    const float* __restrict__ ws1, const float* __restrict__ ws3,
    bf16x8* __restrict__ w1b,  bf16x8* __restrict__ w3b,
    bf16x8* __restrict__ ws1b, bf16x8* __restrict__ ws3b,
    const float* __restrict__ x, const float* __restrict__ gw,
    const float* __restrict__ gb,
    int* __restrict__ cnts, int* __restrict__ lstp, float* __restrict__ lstw,
    unsigned short* __restrict__ xb)
{
    const int b = blockIdx.x;
    if (b < 8704) {
        // ---- weight conversion ----
        int g = b * 256 + threadIdx.x;    // chunk of 8 floats
        const float* s; bf16x8* d; int i;
        if      (g < 1048576) { s = w1;  d = w1b;  i = g; }            // 16*512*1024/8
        else if (g < 2097152) { s = w3;  d = w3b;  i = g - 1048576; }
        else if (g < 2162688) { s = ws1; d = ws1b; i = g - 2097152; }  // 512*1024/8
        else                  { s = ws3; d = ws3b; i = g - 2162688; }
        f32x8 v = ((const f32x8*)s)[i];
        d[i] = cvt8(v);
        return;
    }
    // ---- gate: scores + top-k selection + x->bf16 + list build ----
    int tok  = (b - 8704) * 4 + (threadIdx.x >> 6);   // one wave per token
    int lane = threadIdx.x & 63;
    const float* xp = x + (size_t)tok * DIMD;
    float xv[16];
#pragma unroll
    for (int j = 0; j < 16; ++j) xv[j] = xp[j * 64 + lane];

    unsigned short* xbp = xb + (size_t)tok * DIMD;
#pragma unroll
    for (int j = 0; j < 16; ++j) xbp[j * 64 + lane] = f2b(xv[j]);

    float sc[16];
#pragma unroll
    for (int e = 0; e < 16; ++e) {
        const float* gwe = gw + e * DIMD;
        float p0 = 0.f, p1 = 0.f;
#pragma unroll
        for (int j = 0; j < 16; j += 2) {
            p0 += xv[j]     * gwe[j * 64 + lane];
            p1 += xv[j + 1] * gwe[(j + 1) * 64 + lane];
        }
        float p = p0 + p1;
#pragma unroll
        for (int o = 32; o; o >>= 1) p += __shfl_xor(p, o, 64);
        sc[e] = p;
    }
    if (lane != 0) return;

    float orig[16], s[16];
#pragma unroll
    for (int e = 0; e < 16; ++e) {
        orig[e] = 1.f / (1.f + expf(-sc[e]));
        s[e] = orig[e] + gb[e];
    }
    float gmax[4];
#pragma unroll
    for (int g = 0; g < 4; ++g) {
        float m = s[4 * g];
        for (int j = 1; j < 4; ++j) m = fmaxf(m, s[4 * g + j]);
        gmax[g] = m;
    }
    int g0 = 0;
    for (int g = 1; g < 4; ++g) if (gmax[g] > gmax[g0]) g0 = g;
    int g1 = -1;
    for (int g = 0; g < 4; ++g) { if (g == g0) continue; if (g1 < 0 || gmax[g] > gmax[g1]) g1 = g; }
    unsigned keep = (0xFu << (4 * g0)) | (0xFu << (4 * g1));
    unsigned used = 0;
    for (int j = 0; j < 4; ++j) {
        int best = -1;
        for (int e = 0; e < 16; ++e) {
            if (!((keep >> e) & 1u) || ((used >> e) & 1u)) continue;
            if (best < 0 || s[e] > s[best]) best = e;
        }
        used |= 1u << best;
        int pos = atomicAdd(&cnts[best], 1);     // list order irrelevant: rows independent
        lstp[best * T_TOK + pos] = tok | (j << 16);
        lstw[best * T_TOK + pos] = orig[best];
    }
}

// ---------- GEMM1: H = silu(X W1^T) * (X W3^T) ----------
// Block tile 128m x 128n, wave tile 64x64 (dual h1/h3), BK=64.
// XCD-affine grid; swizzled LDS; 2-deep register prefetch for streamed W
// panels (A/xb is L2-warm, 1-deep). grid: 1024 routed + 64 shared = 1088.
__global__ __launch_bounds__(256, 2) void gemm1_kernel(
    const unsigned short* __restrict__ xb,
    const unsigned short* __restrict__ w1b,
    const unsigned short* __restrict__ w3b,
    const unsigned short* __restrict__ ws1b,
    const unsigned short* __restrict__ ws3b,
    const int* __restrict__ counts,
    const int* __restrict__ lst,
    unsigned short* __restrict__ H)
{
    int b = blockIdx.x;
    int seg, mt, nt;
    if (b < 1024) {
        int xcd = b & 7, slot = b >> 3;     // slot 0..127
        seg = xcd + 8 * (slot >> 6);        // 2 experts per XCD
        int tile = slot & 63;
        mt = tile >> 2; nt = tile & 3;      // mt 0..15, nt 0..3
    } else {
        seg = NEXP;
        int tile = b - 1024;                // 0..63
        mt = tile >> 2; nt = tile & 3;
    }
    const int n_e = (seg == NEXP) ? T_TOK : counts[seg];
    const int m0  = mt * 128;
    if (m0 >= n_e) return;
    const int n0  = nt * 128;

    const unsigned short* w1p = (seg == NEXP) ? ws1b : w1b + (size_t)seg * INTERI * DIMD;
    const unsigned short* w3p = (seg == NEXP) ? ws3b : w3b + (size_t)seg * INTERI * DIMD;
    const int* lste = lst + seg * T_TOK;

    __shared__ __align__(16) unsigned short lA [2][128][32];   // 16 KB
    __shared__ __align__(16) unsigned short lB1[2][128][32];   // 16 KB
    __shared__ __align__(16) unsigned short lB3[2][128][32];   // 16 KB

    const int tid  = threadIdx.x;
    const int wave = tid >> 6;
    const int lane = tid & 63;
    const int quad = lane >> 4;
    const int lrow = lane & 15;
    const int r4   = tid >> 2;        // 0..63 staging row
    const int ct   = tid & 3;         // chunk index

    int ra0 = m0 + r4;       if (ra0 > n_e - 1) ra0 = n_e - 1;
    int ra1 = m0 + r4 + 64;  if (ra1 > n_e - 1) ra1 = n_e - 1;
    int tok0 = (seg == NEXP) ? ra0 : (lste[ra0] & 0xFFFF);
    int tok1 = (seg == NEXP) ? ra1 : (lste[ra1] & 0xFFFF);
    const unsigned short* gA0  = xb  + (size_t)tok0 * DIMD + ct * 8;
    const unsigned short* gA1  = xb  + (size_t)tok1 * DIMD + ct * 8;
    const unsigned short* gB1a = w1p + (size_t)(n0 + r4)      * DIMD + ct * 8;
    const unsigned short* gB1b = w1p + (size_t)(n0 + r4 + 64) * DIMD + ct * 8;
    const unsigned short* gB3a = w3p + (size_t)(n0 + r4)      * DIMD + ct * 8;
    const unsigned short* gB3b = w3p + (size_t)(n0 + r4 + 64) * DIMD + ct * 8;

    bf16x8 pa[2][2];                       // A staging (1-deep): [half][kk]
    bf16x8 p1A[2][2], p1B[2][2];           // W1 staging (2-deep parity)
    bf16x8 p3A[2][2], p3B[2][2];           // W3 staging (2-deep parity)

#define G1LOADA(k0) do { _Pragma("unroll") for (int kk = 0; kk < 2; ++kk) { \
    pa[0][kk] = *(const bf16x8*)(gA0 + (k0) + kk * 32); \
    pa[1][kk] = *(const bf16x8*)(gA1 + (k0) + kk * 32); } } while (0)

#define G1LOADW_A(k0) do { _Pragma("unroll") for (int kk = 0; kk < 2; ++kk) { \
    p1A[0][kk] = *(const bf16x8*)(gB1a + (k0) + kk * 32); \
    p1A[1][kk] = *(const bf16x8*)(gB1b + (k0) + kk * 32); \
    p3A[0][kk] = *(const bf16x8*)(gB3a + (k0) + kk * 32); \
    p3A[1][kk] = *(const bf16x8*)(gB3b + (k0) + kk * 32); } } while (0)

#define G1LOADW_B(k0) do { _Pragma("unroll") for (int kk = 0; kk < 2; ++kk) { \
    p1B[0][kk] = *(const bf16x8*)(gB1a + (k0) + kk * 32); \
    p1B[1][kk] = *(const bf16x8*)(gB1b + (k0) + kk * 32); \
    p3B[0][kk] = *(const bf16x8*)(gB3a + (k0) + kk * 32); \
    p3B[1][kk] = *(const bf16x8*)(gB3b + (k0) + kk * 32); } } while (0)

#define G1STORE(P1, P3) do { _Pragma("unroll") for (int kk = 0; kk < 2; ++kk) { \
    *(bf16x8*)&lA [kk][r4]     [SW(r4, ct)]      = pa[0][kk]; \
    *(bf16x8*)&lA [kk][64 + r4][SW(64 + r4, ct)] = pa[1][kk]; \
    *(bf16x8*)&lB1[kk][r4]     [SW(r4, ct)]      = P1[0][kk]; \
    *(bf16x8*)&lB1[kk][64 + r4][SW(64 + r4, ct)] = P1[1][kk]; \
    *(bf16x8*)&lB3[kk][r4]     [SW(r4, ct)]      = P3[0][kk]; \
    *(bf16x8*)&lB3[kk][64 + r4][SW(64 + r4, ct)] = P3[1][kk]; } } while (0)

    f32x4 acc1[4][4], acc3[4][4];
    const f32x4 zero = {0.f, 0.f, 0.f, 0.f};
#pragma unroll
    for (int i = 0; i < 4; ++i)
#pragma unroll
        for (int j = 0; j < 4; ++j) { acc1[i][j] = zero; acc3[i][j] = zero; }

    const int wm = (wave & 1) * 64;
    const int wn = (wave >> 1) * 64;

    // compute one BK=64 step from LDS; b1/b3 share one fragment set (reg relief)
#define G1COMPUTE() do { _Pragma("unroll") for (int kk = 0; kk < 2; ++kk) { \
    bf16x8 a[4], bv[4]; \
    _Pragma("unroll") for (int t = 0; t < 4; ++t) { \
        int rr = wm + t * 16 + lrow; \
        a[t] = *(const bf16x8*)&lA[kk][rr][SW(rr, quad)]; } \
    _Pragma("unroll") for (int t = 0; t < 4; ++t) { \
        int rc = wn + t * 16 + lrow; \
        bv[t] = *(const bf16x8*)&lB1[kk][rc][SW(rc, quad)]; } \
    _Pragma("unroll") for (int i = 0; i < 4; ++i) \
    _Pragma("unroll") for (int j = 0; j < 4; ++j) \
        acc1[i][j] = __builtin_amdgcn_mfma_f32_16x16x32_bf16(a[i], bv[j], acc1[i][j], 0, 0, 0); \
    _Pragma("unroll") for (int t = 0; t < 4; ++t) { \
        int rc = wn + t * 16 + lrow; \
        bv[t] = *(const bf16x8*)&lB3[kk][rc][SW(rc, quad)]; } \
    _Pragma("unroll") for (int i = 0; i < 4; ++i) \
    _Pragma("unroll") for (int j = 0; j < 4; ++j) \
        acc3[i][j] = __builtin_amdgcn_mfma_f32_16x16x32_bf16(a[i], bv[j], acc3[i][j], 0, 0, 0); \
    } } while (0)

    // prologue: A panel 0 (1-deep), W panels 0 and 1 (2-deep)
    G1LOADA(0); G1LOADW_A(0); G1LOADW_B(64);
    for (int it2 = 0; it2 < 8; ++it2) {                  // NK=16, 2 steps/iter
        // even step it = 2*it2 (parity A)
        G1STORE(p1A, p3A);
        lds_barrier();
        G1LOADA((2 * it2 + 1) * 64);
        if (it2 < 7) G1LOADW_A((2 * it2 + 2) * 64);
        G1COMPUTE();
        lds_barrier();
        // odd step it = 2*it2+1 (parity B)
        G1STORE(p1B, p3B);
        lds_barrier();
        if (it2 < 7) { G1LOADA((2 * it2 + 2) * 64); G1LOADW_B((2 * it2 + 3) * 64); }
        G1COMPUTE();
        lds_barrier();
    }
#undef G1LOADA
#undef G1LOADW_A
#undef G1LOADW_B
#undef G1STORE
#undef G1COMPUTE

    unsigned short* Hseg = H + (size_t)seg * T_TOK * INTERI;
#pragma unroll
    for (int i = 0; i < 4; ++i) {
        int rbase = m0 + wm + i * 16 + quad * 4;
#pragma unroll
        for (int r = 0; r < 4; ++r) {
            int row = rbase + r;
            if (row >= n_e) continue;
            unsigned short* hrow = Hseg + (size_t)row * INTERI + n0 + wn + lrow;
#pragma unroll
            for (int j = 0; j < 4; ++j) {
                float v1 = acc1[i][j][r];
                float v3 = acc3[i][j][r];
                float hv = (v1 / (1.f + __expf(-v1))) * v3;   // silu(v1)*v3
                hrow[j * 16] = f2b(hv);
            }
        }
    }
}

// ---------- GEMM2: P[slot] = w * (H W2^T), 128x128 tile, atomic-free ----------
// B operand (w2/ws2) consumed fp32, converted to bf16 at LDS-store time.
// Full 2-deep register prefetch (H and w2 both streamed).
// grid: 2048 routed slots + 128 shared = 2176.
__global__ __launch_bounds__(256, 2) void gemm2_kernel(
    const unsigned short* __restrict__ H,
    const float* __restrict__ w2f,
    const float* __restrict__ ws2f,
    const int* __restrict__ counts,
    const int* __restrict__ lst,
    const float* __restrict__ lstw,
    float* __restrict__ P)
{
    int b = blockIdx.x;
    int seg, mt, nt;
    if (b < 2048) {
        int xcd = b & 7, slot = b >> 3;     // 0..255
        seg = xcd + 8 * (slot >> 7);
        int tile = slot & 127;
        mt = tile >> 3; nt = tile & 7;      // mt 0..15, nt 0..7
    } else {
        seg = NEXP;
        int tile = b - 2048;                // 0..127
        mt = tile >> 3; nt = tile & 7;
    }
    const int n_e = (seg == NEXP) ? T_TOK : counts[seg];
    const int m0  = mt * 128;
    if (m0 >= n_e) return;
    const int n0  = nt * 128;

    const float* w2p = (seg == NEXP) ? ws2f : w2f + (size_t)seg * DIMD * INTERI;
    const unsigned short* Hseg = H + (size_t)seg * T_TOK * INTERI;

    __shared__ __align__(16) unsigned short lA[2][128][32];   // 16 KB
    __shared__ __align__(16) unsigned short lB[2][128][32];   // 16 KB

    const int tid  = threadIdx.x;
    const int wave = tid >> 6;
    const int lane = tid & 63;
    const int quad = lane >> 4;
    const int lrow = lane & 15;
    const int r4   = tid >> 2;
    const int ct   = tid & 3;

    int ra0 = m0 + r4;       if (ra0 > n_e - 1) ra0 = n_e - 1;
    int ra1 = m0 + r4 + 64;  if (ra1 > n_e - 1) ra1 = n_e - 1;
    const unsigned short* gA0 = Hseg + (size_t)ra0 * INTERI + ct * 8;
    const unsigned short* gA1 = Hseg + (size_t)ra1 * INTERI + ct * 8;
    const float* gB0 = w2p + (size_t)(n0 + r4)      * INTERI + ct * 8;
    const float* gB1 = w2p + (size_t)(n0 + r4 + 64) * INTERI + ct * 8;

    bf16x8 paA[2][2], paB[2][2];   // H staging, 2-deep
    f32x8  pbA[2][2], pbB[2][2];   // w2 staging (fp32), 2-deep

#define G2LOAD_A(k0) do { _Pragma("unroll") for (int kk = 0; kk < 2; ++kk) { \
    paA[0][kk] = *(const bf16x8*)(gA0 + (k0) + kk * 32); \
    paA[1][kk] = *(const bf16x8*)(gA1 + (k0) + kk * 32); \
    pbA[0][kk] = *(const f32x8*)(gB0 + (k0) + kk * 32); \
    pbA[1][kk] = *(const f32x8*)(gB1 + (k0) + kk * 32); } } while (0)

#define G2LOAD_B(k0) do { _Pragma("unroll") for (int kk = 0; kk < 2; ++kk) { \
    paB[0][kk] = *(const bf16x8*)(gA0 + (k0) + kk * 32); \
    paB[1][kk] = *(const bf16x8*)(gA1 + (k0) + kk * 32); \
    pbB[0][kk] = *(const f32x8*)(gB0 + (k0) + kk * 32); \
    pbB[1][kk] = *(const f32x8*)(gB1 + (k0) + kk * 32); } } while (0)

#define G2STORE(PA, PB) do { _Pragma("unroll") for (int kk = 0; kk < 2; ++kk) { \
    *(bf16x8*)&lA[kk][r4]     [SW(r4, ct)]      = PA[0][kk]; \
    *(bf16x8*)&lA[kk][64 + r4][SW(64 + r4, ct)] = PA[1][kk]; \
    *(bf16x8*)&lB[kk][r4]     [SW(r4, ct)]      = cvt8(PB[0][kk]); \
    *(bf16x8*)&lB[kk][64 + r4][SW(64 + r4, ct)] = cvt8(PB[1][kk]); } } while (0)

    f32x4 acc[4][4];
    const f32x4 zero = {0.f, 0.f, 0.f, 0.f};
#pragma unroll
    for (int i = 0; i < 4; ++i)
#pragma unroll
        for (int j = 0; j < 4; ++j) acc[i][j] = zero;

    const int wm = (wave & 1) * 64;
    const int wn = (wave >> 1) * 64;

#define G2COMPUTE() do { _Pragma("unroll") for (int kk = 0; kk < 2; ++kk) { \
    bf16x8 a[4], bv[4]; \
    _Pragma("unroll") for (int t = 0; t < 4; ++t) { \
        int rr = wm + t * 16 + lrow; \
        a[t] = *(const bf16x8*)&lA[kk][rr][SW(rr, quad)]; } \
    _Pragma("unroll") for (int t = 0; t < 4; ++t) { \
        int rc = wn + t * 16 + lrow; \
        bv[t] = *(const bf16x8*)&lB[kk][rc][SW(rc, quad)]; } \
    _Pragma("unroll") for (int i = 0; i < 4; ++i) \
    _Pragma("unroll") for (int j = 0; j < 4; ++j) \
        acc[i][j] = __builtin_amdgcn_mfma_f32_16x16x32_bf16(a[i], bv[j], acc[i][j], 0, 0, 0); \
    } } while (0)

    G2LOAD_A(0); G2LOAD_B(64);
    for (int it2 = 0; it2 < 4; ++it2) {                  // NK=8, 2 steps/iter
        G2STORE(paA, pbA);
        lds_barrier();
        if (it2 < 3) G2LOAD_A((2 * it2 + 2) * 64);
        G2COMPUTE();
        lds_barrier();
        G2STORE(paB, pbB);
        lds_barrier();
        if (it2 < 3) G2LOAD_B((2 * it2 + 3) * 64);
        G2COMPUTE();
        lds_barrier();
    }
#undef G2LOAD_A
#undef G2LOAD_B
#undef G2STORE
#undef G2COMPUTE

#pragma unroll
    for (int i = 0; i < 4; ++i) {
        int rbase = m0 + wm + i * 16 + quad * 4;
#pragma unroll
        for (int r = 0; r < 4; ++r) {
            int row = rbase + r;
            if (row >= n_e) continue;
            int tok, slot; float wt;
            if (seg == NEXP) { tok = row; slot = 4; wt = 1.f; }
            else {
                int ent = lst[seg * T_TOK + row];
                tok = ent & 0xFFFF; slot = ent >> 16;
                wt = lstw[seg * T_TOK + row];
            }
            float* prow = P + ((size_t)slot * T_TOK + tok) * DIMD + n0 + wn + lrow;
#pragma unroll
            for (int j = 0; j < 4; ++j)
                prow[j * 16] = wt * acc[i][j][r];
        }
    }
}

// ---------- combine: y = P0+P1+P2+P3+P4 ----------
__global__ __launch_bounds__(256) void combine_kernel(
    const float4* __restrict__ P, float4* __restrict__ y)
{
    const int i = blockIdx.x * 256 + threadIdx.x;   // over T*D/4
    const size_t plane = (size_t)T_TOK * DIMD / 4;
    float4 a = P[i];
    float4 b = P[plane + i];
    float4 c = P[2 * plane + i];
    float4 d = P[3 * plane + i];
    float4 e = P[4 * plane + i];
    float4 o;
    o.x = a.x + b.x + c.x + d.x + e.x;
    o.y = a.y + b.y + c.y + d.y + e.y;
    o.z = a.z + b.z + c.z + d.z + e.z;
    o.w = a.w + b.w + c.w + d.w + e.w;
    y[i] = o;
}

// ---------- launcher ----------
extern "C" void kernel_launch(void* const* d_in, const int* in_sizes, int n_in,
                              void* d_out, int out_size, void* d_ws, size_t ws_size,
                              hipStream_t stream)
{
    const float* x   = (const float*)d_in[0];
    const float* gw  = (const float*)d_in[1];
    const float* gb  = (const float*)d_in[2];
    const float* w1  = (const float*)d_in[3];
    const float* w2  = (const float*)d_in[4];
    const float* w3  = (const float*)d_in[5];
    const float* ws1 = (const float*)d_in[6];
    const float* ws2 = (const float*)d_in[7];
    const float* ws3 = (const float*)d_in[8];

    char* base = (char*)d_ws;
    size_t off = 0;
    auto alloc = [&](size_t bytes) {
        char* q = base + off; off += (bytes + 255) & ~(size_t)255; return q;
    };
    unsigned short* xb   = (unsigned short*)alloc((size_t)T_TOK * DIMD * 2);
    unsigned short* w1b  = (unsigned short*)alloc((size_t)NEXP * INTERI * DIMD * 2);
    unsigned short* w3b  = (unsigned short*)alloc((size_t)NEXP * INTERI * DIMD * 2);
    unsigned short* ws1b = (unsigned short*)alloc((size_t)INTERI * DIMD * 2);
    unsigned short* ws3b = (unsigned short*)alloc((size_t)INTERI * DIMD * 2);
    unsigned short* Hb   = (unsigned short*)alloc((size_t)NSEG * T_TOK * INTERI * 2);
    int*            cnts = (int*)alloc(NEXP * 4);
    int*            lstp = (int*)alloc((size_t)NEXP * T_TOK * 4);
    float*          lstw = (float*)alloc((size_t)NEXP * T_TOK * 4);
    float*          Pb   = (float*)alloc((size_t)5 * T_TOK * DIMD * 4);

    hipMemsetAsync(cnts, 0, NEXP * sizeof(int), stream);
    // prep grid: 8704 cvt blocks + 512 gate blocks
    prep_kernel<<<9216, 256, 0, stream>>>(w1, w3, ws1, ws3,
                                          (bf16x8*)w1b, (bf16x8*)w3b,
                                          (bf16x8*)ws1b, (bf16x8*)ws3b,
                                          x, gw, gb, cnts, lstp, lstw, xb);
    gemm1_kernel<<<1088, 256, 0, stream>>>(xb, w1b, w3b, ws1b, ws3b, cnts, lstp, Hb);
    gemm2_kernel<<<2176, 256, 0, stream>>>(Hb, w2, ws2, cnts, lstp, lstw, Pb);
    combine_kernel<<<(T_TOK * DIMD / 4) / 256, 256, 0, stream>>>((const float4*)Pb, (float4*)d_out);
}

// Round 5
// 254.546 us; speedup vs baseline: 1.3201x; 1.3201x over previous
//
#include <hip/hip_runtime.h>

#define T_TOK  2048
#define DIMD   1024
#define INTERI 512
#define NEXP   16
#define NSEG   17   // 16 routed + 1 shared (index 16)

typedef __bf16 bf16x8 __attribute__((ext_vector_type(8)));
typedef float  f32x4  __attribute__((ext_vector_type(4)));
typedef float  f32x8  __attribute__((ext_vector_type(8)));
typedef unsigned short u16x8 __attribute__((ext_vector_type(8)));

// XOR-swizzle: chunk c (8 elems) of row r lives at slot (c + (r>>1)) & 3.
// Makes b128 reads (lrow=lane&15 varying) conflict-free per quarter-wave.
#define SW(row, c) ((((c) + ((row) >> 1)) & 3) * 8)

// ---------- helpers ----------
__device__ __forceinline__ unsigned short f2b(float f) {
    union { float f; unsigned int u; } c; c.f = f;
    unsigned int u = c.u;
    unsigned int r = (u + 0x7FFFu + ((u >> 16) & 1u)) >> 16;  // RNE
    return (unsigned short)r;
}

// fp32x8 -> bf16x8 (RNE)
__device__ __forceinline__ bf16x8 cvt8(f32x8 v) {
    bf16x8 r;
#pragma unroll
    for (int i = 0; i < 8; ++i) r[i] = (__bf16)v[i];
    return r;
}

// raw barrier: waits only LDS ops, leaves global loads in flight
__device__ __forceinline__ void lds_barrier() {
    asm volatile("s_waitcnt lgkmcnt(0)" ::: "memory");
    __builtin_amdgcn_s_barrier();
}

// ---------- fp32 -> bf16 conversion: w1, w3, ws1, ws3 only ----------
// (x is converted inside the gate kernel; w2/ws2 are consumed fp32 by gemm2.)
__global__ __launch_bounds__(256) void cvt_w_kernel(
    const float* __restrict__ w1,  const float* __restrict__ w3,
    const float* __restrict__ ws1, const float* __restrict__ ws3,
    unsigned short* __restrict__ w1b,  unsigned short* __restrict__ w3b,
    unsigned short* __restrict__ ws1b, unsigned short* __restrict__ ws3b)
{
    int g = blockIdx.x * 256 + threadIdx.x;    // chunk of 8 floats
    const float* s; unsigned short* d; int i;
    if      (g < 1048576) { s = w1;  d = w1b;  i = g; }            // 16*512*1024/8
    else if (g < 2097152) { s = w3;  d = w3b;  i = g - 1048576; }
    else if (g < 2162688) { s = ws1; d = ws1b; i = g - 2097152; }  // 512*1024/8
    else                  { s = ws3; d = ws3b; i = g - 2162688; }
    float4 v0 = ((const float4*)s)[2 * i];
    float4 v1 = ((const float4*)s)[2 * i + 1];
    u16x8 o;
    o[0] = f2b(v0.x); o[1] = f2b(v0.y); o[2] = f2b(v0.z); o[3] = f2b(v0.w);
    o[4] = f2b(v1.x); o[5] = f2b(v1.y); o[6] = f2b(v1.z); o[7] = f2b(v1.w);
    ((u16x8*)d)[i] = o;
}

// ---------- gate phase 1: scores + top-k selection + x->bf16, NO atomics ----------
__global__ __launch_bounds__(256) void gate_score_kernel(
    const float* __restrict__ x, const float* __restrict__ gw,
    const float* __restrict__ gb,
    unsigned* __restrict__ sel, float4* __restrict__ selw,
    unsigned short* __restrict__ xb)
{
    int tok  = blockIdx.x * 4 + (threadIdx.x >> 6);   // one wave per token
    int lane = threadIdx.x & 63;
    const float* xp = x + (size_t)tok * DIMD;
    float xv[16];
#pragma unroll
    for (int j = 0; j < 16; ++j) xv[j] = xp[j * 64 + lane];

    // emit bf16 copy of x (fused conversion; all lanes)
    unsigned short* xbp = xb + (size_t)tok * DIMD;
#pragma unroll
    for (int j = 0; j < 16; ++j) xbp[j * 64 + lane] = f2b(xv[j]);

    float sc[16];
#pragma unroll
    for (int e = 0; e < 16; ++e) {
        const float* gwe = gw + e * DIMD;
        float p0 = 0.f, p1 = 0.f;
#pragma unroll
        for (int j = 0; j < 16; j += 2) {
            p0 += xv[j]     * gwe[j * 64 + lane];
            p1 += xv[j + 1] * gwe[(j + 1) * 64 + lane];
        }
        float p = p0 + p1;
#pragma unroll
        for (int o = 32; o; o >>= 1) p += __shfl_xor(p, o, 64);
        sc[e] = p;
    }
    if (lane != 0) return;

    float orig[16], s[16];
#pragma unroll
    for (int e = 0; e < 16; ++e) {
        orig[e] = 1.f / (1.f + expf(-sc[e]));
        s[e] = orig[e] + gb[e];
    }
    float gmax[4];
#pragma unroll
    for (int g = 0; g < 4; ++g) {
        float m = s[4 * g];
        for (int j = 1; j < 4; ++j) m = fmaxf(m, s[4 * g + j]);
        gmax[g] = m;
    }
    int g0 = 0;
    for (int g = 1; g < 4; ++g) if (gmax[g] > gmax[g0]) g0 = g;
    int g1 = -1;
    for (int g = 0; g < 4; ++g) { if (g == g0) continue; if (g1 < 0 || gmax[g] > gmax[g1]) g1 = g; }
    unsigned keep = (0xFu << (4 * g0)) | (0xFu << (4 * g1));
    unsigned used = 0;
    unsigned pk = 0;
    float w4[4];
    for (int j = 0; j < 4; ++j) {
        int best = -1;
        for (int e = 0; e < 16; ++e) {
            if (!((keep >> e) & 1u) || ((used >> e) & 1u)) continue;
            if (best < 0 || s[e] > s[best]) best = e;
        }
        used |= 1u << best;
        pk |= ((unsigned)best) << (4 * j);
        w4[j] = orig[best];
    }
    sel[tok] = pk;
    selw[tok] = make_float4(w4[0], w4[1], w4[2], w4[3]);
}

// ---------- gate phase 2: build per-expert token lists, NO atomics ----------
// lst entry packs token (low 16) | slot index (bits 16..17).
__global__ __launch_bounds__(256) void build_lists_kernel(
    const unsigned* __restrict__ sel, const float4* __restrict__ selw,
    int* __restrict__ counts, int* __restrict__ lst, float* __restrict__ lstw)
{
    const int e    = blockIdx.x;
    const int tid  = threadIdx.x;
    const int wave = tid >> 6;
    const int lane = tid & 63;

    __shared__ int wsum[4];
    __shared__ int basev;
    if (tid == 0) basev = 0;
    __syncthreads();

    for (int c = 0; c < T_TOK / 256; ++c) {
        int t = c * 256 + tid;
        unsigned s = sel[t];
        int match = -1;
#pragma unroll
        for (int j = 0; j < 4; ++j)
            if (((s >> (4 * j)) & 15u) == (unsigned)e) match = j;
        unsigned long long m = __ballot(match >= 0);
        int wpre = __popcll(m & ((1ull << lane) - 1ull));
        if (lane == 0) wsum[wave] = __popcll(m);
        __syncthreads();
        int pre = basev;
        for (int wv = 0; wv < wave; ++wv) pre += wsum[wv];
        if (match >= 0) {
            int pos = pre + wpre;
            lst [e * T_TOK + pos] = t | (match << 16);
            const float* wp = (const float*)&selw[t];
            lstw[e * T_TOK + pos] = wp[match];
        }
        __syncthreads();
        if (tid == 0) basev += wsum[0] + wsum[1] + wsum[2] + wsum[3];
        __syncthreads();
    }
    if (tid == 0) counts[e] = basev;
}

// ---------- GEMM1: H = silu(X W1^T) * (X W3^T) ----------
// Block tile 128m x 128n, wave tile 64x64 (dual h1/h3), BK=64.
// XCD-affine grid; swizzled LDS; 2-deep register prefetch for streamed W
// panels (A/xb is L2-warm, 1-deep). grid: 1024 routed + 64 shared = 1088.
__global__ __launch_bounds__(256, 2) void gemm1_kernel(
    const unsigned short* __restrict__ xb,
    const unsigned short* __restrict__ w1b,
    const unsigned short* __restrict__ w3b,
    const unsigned short* __restrict__ ws1b,
    const unsigned short* __restrict__ ws3b,
    const int* __restrict__ counts,
    const int* __restrict__ lst,
    unsigned short* __restrict__ H)
{
    int b = blockIdx.x;
    int seg, mt, nt;
    if (b < 1024) {
        int xcd = b & 7, slot = b >> 3;     // slot 0..127
        seg = xcd + 8 * (slot >> 6);        // 2 experts per XCD
        int tile = slot & 63;
        mt = tile >> 2; nt = tile & 3;      // mt 0..15, nt 0..3
    } else {
        seg = NEXP;
        int tile = b - 1024;                // 0..63
        mt = tile >> 2; nt = tile & 3;
    }
    const int n_e = (seg == NEXP) ? T_TOK : counts[seg];
    const int m0  = mt * 128;
    if (m0 >= n_e) return;
    const int n0  = nt * 128;

    const unsigned short* w1p = (seg == NEXP) ? ws1b : w1b + (size_t)seg * INTERI * DIMD;
    const unsigned short* w3p = (seg == NEXP) ? ws3b : w3b + (size_t)seg * INTERI * DIMD;
    const int* lste = lst + seg * T_TOK;

    __shared__ __align__(16) unsigned short lA [2][128][32];   // 16 KB
    __shared__ __align__(16) unsigned short lB1[2][128][32];   // 16 KB
    __shared__ __align__(16) unsigned short lB3[2][128][32];   // 16 KB

    const int tid  = threadIdx.x;
    const int wave = tid >> 6;
    const int lane = tid & 63;
    const int quad = lane >> 4;
    const int lrow = lane & 15;
    const int r4   = tid >> 2;        // 0..63 staging row
    const int ct   = tid & 3;         // chunk index

    int ra0 = m0 + r4;       if (ra0 > n_e - 1) ra0 = n_e - 1;
    int ra1 = m0 + r4 + 64;  if (ra1 > n_e - 1) ra1 = n_e - 1;
    int tok0 = (seg == NEXP) ? ra0 : (lste[ra0] & 0xFFFF);
    int tok1 = (seg == NEXP) ? ra1 : (lste[ra1] & 0xFFFF);
    const unsigned short* gA0  = xb  + (size_t)tok0 * DIMD + ct * 8;
    const unsigned short* gA1  = xb  + (size_t)tok1 * DIMD + ct * 8;
    const unsigned short* gB1a = w1p + (size_t)(n0 + r4)      * DIMD + ct * 8;
    const unsigned short* gB1b = w1p + (size_t)(n0 + r4 + 64) * DIMD + ct * 8;
    const unsigned short* gB3a = w3p + (size_t)(n0 + r4)      * DIMD + ct * 8;
    const unsigned short* gB3b = w3p + (size_t)(n0 + r4 + 64) * DIMD + ct * 8;

    bf16x8 pa[2][2];                       // A staging (1-deep): [half][kk]
    bf16x8 p1A[2][2], p1B[2][2];           // W1 staging (2-deep parity)
    bf16x8 p3A[2][2], p3B[2][2];           // W3 staging (2-deep parity)

#define G1LOADA(k0) do { _Pragma("unroll") for (int kk = 0; kk < 2; ++kk) { \
    pa[0][kk] = *(const bf16x8*)(gA0 + (k0) + kk * 32); \
    pa[1][kk] = *(const bf16x8*)(gA1 + (k0) + kk * 32); } } while (0)

#define G1LOADW_A(k0) do { _Pragma("unroll") for (int kk = 0; kk < 2; ++kk) { \
    p1A[0][kk] = *(const bf16x8*)(gB1a + (k0) + kk * 32); \
    p1A[1][kk] = *(const bf16x8*)(gB1b + (k0) + kk * 32); \
    p3A[0][kk] = *(const bf16x8*)(gB3a + (k0) + kk * 32); \
    p3A[1][kk] = *(const bf16x8*)(gB3b + (k0) + kk * 32); } } while (0)

#define G1LOADW_B(k0) do { _Pragma("unroll") for (int kk = 0; kk < 2; ++kk) { \
    p1B[0][kk] = *(const bf16x8*)(gB1a + (k0) + kk * 32); \
    p1B[1][kk] = *(const bf16x8*)(gB1b + (k0) + kk * 32); \
    p3B[0][kk] = *(const bf16x8*)(gB3a + (k0) + kk * 32); \
    p3B[1][kk] = *(const bf16x8*)(gB3b + (k0) + kk * 32); } } while (0)

#define G1STORE(P1, P3) do { _Pragma("unroll") for (int kk = 0; kk < 2; ++kk) { \
    *(bf16x8*)&lA [kk][r4]     [SW(r4, ct)]      = pa[0][kk]; \
    *(bf16x8*)&lA [kk][64 + r4][SW(64 + r4, ct)] = pa[1][kk]; \
    *(bf16x8*)&lB1[kk][r4]     [SW(r4, ct)]      = P1[0][kk]; \
    *(bf16x8*)&lB1[kk][64 + r4][SW(64 + r4, ct)] = P1[1][kk]; \
    *(bf16x8*)&lB3[kk][r4]     [SW(r4, ct)]      = P3[0][kk]; \
    *(bf16x8*)&lB3[kk][64 + r4][SW(64 + r4, ct)] = P3[1][kk]; } } while (0)

    f32x4 acc1[4][4], acc3[4][4];
    const f32x4 zero = {0.f, 0.f, 0.f, 0.f};
#pragma unroll
    for (int i = 0; i < 4; ++i)
#pragma unroll
        for (int j = 0; j < 4; ++j) { acc1[i][j] = zero; acc3[i][j] = zero; }

    const int wm = (wave & 1) * 64;
    const int wn = (wave >> 1) * 64;

    // compute one BK=64 step from LDS; b1/b3 share one fragment set (reg relief)
#define G1COMPUTE() do { _Pragma("unroll") for (int kk = 0; kk < 2; ++kk) { \
    bf16x8 a[4], bv[4]; \
    _Pragma("unroll") for (int t = 0; t < 4; ++t) { \
        int rr = wm + t * 16 + lrow; \
        a[t] = *(const bf16x8*)&lA[kk][rr][SW(rr, quad)]; } \
    _Pragma("unroll") for (int t = 0; t < 4; ++t) { \
        int rc = wn + t * 16 + lrow; \
        bv[t] = *(const bf16x8*)&lB1[kk][rc][SW(rc, quad)]; } \
    _Pragma("unroll") for (int i = 0; i < 4; ++i) \
    _Pragma("unroll") for (int j = 0; j < 4; ++j) \
        acc1[i][j] = __builtin_amdgcn_mfma_f32_16x16x32_bf16(a[i], bv[j], acc1[i][j], 0, 0, 0); \
    _Pragma("unroll") for (int t = 0; t < 4; ++t) { \
        int rc = wn + t * 16 + lrow; \
        bv[t] = *(const bf16x8*)&lB3[kk][rc][SW(rc, quad)]; } \
    _Pragma("unroll") for (int i = 0; i < 4; ++i) \
    _Pragma("unroll") for (int j = 0; j < 4; ++j) \
        acc3[i][j] = __builtin_amdgcn_mfma_f32_16x16x32_bf16(a[i], bv[j], acc3[i][j], 0, 0, 0); \
    } } while (0)

    // prologue: A panel 0 (1-deep), W panels 0 and 1 (2-deep)
    G1LOADA(0); G1LOADW_A(0); G1LOADW_B(64);
    for (int it2 = 0; it2 < 8; ++it2) {                  // NK=16, 2 steps/iter
        // even step it = 2*it2 (parity A)
        G1STORE(p1A, p3A);
        lds_barrier();
        G1LOADA((2 * it2 + 1) * 64);
        if (it2 < 7) G1LOADW_A((2 * it2 + 2) * 64);
        G1COMPUTE();
        lds_barrier();
        // odd step it = 2*it2+1 (parity B)
        G1STORE(p1B, p3B);
        lds_barrier();
        if (it2 < 7) { G1LOADA((2 * it2 + 2) * 64); G1LOADW_B((2 * it2 + 3) * 64); }
        G1COMPUTE();
        lds_barrier();
    }
#undef G1LOADA
#undef G1LOADW_A
#undef G1LOADW_B
#undef G1STORE
#undef G1COMPUTE

    unsigned short* Hseg = H + (size_t)seg * T_TOK * INTERI;
#pragma unroll
    for (int i = 0; i < 4; ++i) {
        int rbase = m0 + wm + i * 16 + quad * 4;
#pragma unroll
        for (int r = 0; r < 4; ++r) {
            int row = rbase + r;
            if (row >= n_e) continue;
            unsigned short* hrow = Hseg + (size_t)row * INTERI + n0 + wn + lrow;
#pragma unroll
            for (int j = 0; j < 4; ++j) {
                float v1 = acc1[i][j][r];
                float v3 = acc3[i][j][r];
                float hv = (v1 / (1.f + __expf(-v1))) * v3;   // silu(v1)*v3
                hrow[j * 16] = f2b(hv);
            }
        }
    }
}

// ---------- GEMM2: P[slot] = w * (H W2^T), 128x128 tile, atomic-free ----------
// B operand (w2/ws2) consumed fp32, converted to bf16 at LDS-store time.
// Full 2-deep register prefetch (H and w2 both streamed).
// grid: 2048 routed slots + 128 shared = 2176.
__global__ __launch_bounds__(256, 2) void gemm2_kernel(
    const unsigned short* __restrict__ H,
    const float* __restrict__ w2f,
    const float* __restrict__ ws2f,
    const int* __restrict__ counts,
    const int* __restrict__ lst,
    const float* __restrict__ lstw,
    float* __restrict__ P)
{
    int b = blockIdx.x;
    int seg, mt, nt;
    if (b < 2048) {
        int xcd = b & 7, slot = b >> 3;     // 0..255
        seg = xcd + 8 * (slot >> 7);
        int tile = slot & 127;
        mt = tile >> 3; nt = tile & 7;      // mt 0..15, nt 0..7
    } else {
        seg = NEXP;
        int tile = b - 2048;                // 0..127
        mt = tile >> 3; nt = tile & 7;
    }
    const int n_e = (seg == NEXP) ? T_TOK : counts[seg];
    const int m0  = mt * 128;
    if (m0 >= n_e) return;
    const int n0  = nt * 128;

    const float* w2p = (seg == NEXP) ? ws2f : w2f + (size_t)seg * DIMD * INTERI;
    const unsigned short* Hseg = H + (size_t)seg * T_TOK * INTERI;

    __shared__ __align__(16) unsigned short lA[2][128][32];   // 16 KB
    __shared__ __align__(16) unsigned short lB[2][128][32];   // 16 KB

    const int tid  = threadIdx.x;
    const int wave = tid >> 6;
    const int lane = tid & 63;
    const int quad = lane >> 4;
    const int lrow = lane & 15;
    const int r4   = tid >> 2;
    const int ct   = tid & 3;

    int ra0 = m0 + r4;       if (ra0 > n_e - 1) ra0 = n_e - 1;
    int ra1 = m0 + r4 + 64;  if (ra1 > n_e - 1) ra1 = n_e - 1;
    const unsigned short* gA0 = Hseg + (size_t)ra0 * INTERI + ct * 8;
    const unsigned short* gA1 = Hseg + (size_t)ra1 * INTERI + ct * 8;
    const float* gB0 = w2p + (size_t)(n0 + r4)      * INTERI + ct * 8;
    const float* gB1 = w2p + (size_t)(n0 + r4 + 64) * INTERI + ct * 8;

    bf16x8 paA[2][2], paB[2][2];   // H staging, 2-deep
    f32x8  pbA[2][2], pbB[2][2];   // w2 staging (fp32), 2-deep

#define G2LOAD_A(k0) do { _Pragma("unroll") for (int kk = 0; kk < 2; ++kk) { \
    paA[0][kk] = *(const bf16x8*)(gA0 + (k0) + kk * 32); \
    paA[1][kk] = *(const bf16x8*)(gA1 + (k0) + kk * 32); \
    pbA[0][kk] = *(const f32x8*)(gB0 + (k0) + kk * 32); \
    pbA[1][kk] = *(const f32x8*)(gB1 + (k0) + kk * 32); } } while (0)

#define G2LOAD_B(k0) do { _Pragma("unroll") for (int kk = 0; kk < 2; ++kk) { \
    paB[0][kk] = *(const bf16x8*)(gA0 + (k0) + kk * 32); \
    paB[1][kk] = *(const bf16x8*)(gA1 + (k0) + kk * 32); \
    pbB[0][kk] = *(const f32x8*)(gB0 + (k0) + kk * 32); \
    pbB[1][kk] = *(const f32x8*)(gB1 + (k0) + kk * 32); } } while (0)

#define G2STORE(PA, PB) do { _Pragma("unroll") for (int kk = 0; kk < 2; ++kk) { \
    *(bf16x8*)&lA[kk][r4]     [SW(r4, ct)]      = PA[0][kk]; \
    *(bf16x8*)&lA[kk][64 + r4][SW(64 + r4, ct)] = PA[1][kk]; \
    *(bf16x8*)&lB[kk][r4]     [SW(r4, ct)]      = cvt8(PB[0][kk]); \
    *(bf16x8*)&lB[kk][64 + r4][SW(64 + r4, ct)] = cvt8(PB[1][kk]); } } while (0)

    f32x4 acc[4][4];
    const f32x4 zero = {0.f, 0.f, 0.f, 0.f};
#pragma unroll
    for (int i = 0; i < 4; ++i)
#pragma unroll
        for (int j = 0; j < 4; ++j) acc[i][j] = zero;

    const int wm = (wave & 1) * 64;
    const int wn = (wave >> 1) * 64;

#define G2COMPUTE() do { _Pragma("unroll") for (int kk = 0; kk < 2; ++kk) { \
    bf16x8 a[4], bv[4]; \
    _Pragma("unroll") for (int t = 0; t < 4; ++t) { \
        int rr = wm + t * 16 + lrow; \
        a[t] = *(const bf16x8*)&lA[kk][rr][SW(rr, quad)]; } \
    _Pragma("unroll") for (int t = 0; t < 4; ++t) { \
        int rc = wn + t * 16 + lrow; \
        bv[t] = *(const bf16x8*)&lB[kk][rc][SW(rc, quad)]; } \
    _Pragma("unroll") for (int i = 0; i < 4; ++i) \
    _Pragma("unroll") for (int j = 0; j < 4; ++j) \
        acc[i][j] = __builtin_amdgcn_mfma_f32_16x16x32_bf16(a[i], bv[j], acc[i][j], 0, 0, 0); \
    } } while (0)

    G2LOAD_A(0); G2LOAD_B(64);
    for (int it2 = 0; it2 < 4; ++it2) {                  // NK=8, 2 steps/iter
        G2STORE(paA, pbA);
        lds_barrier();
        if (it2 < 3) G2LOAD_A((2 * it2 + 2) * 64);
        G2COMPUTE();
        lds_barrier();
        G2STORE(paB, pbB);
        lds_barrier();
        if (it2 < 3) G2LOAD_B((2 * it2 + 3) * 64);
        G2COMPUTE();
        lds_barrier();
    }
#undef G2LOAD_A
#undef G2LOAD_B
#undef G2STORE
#undef G2COMPUTE

#pragma unroll
    for (int i = 0; i < 4; ++i) {
        int rbase = m0 + wm + i * 16 + quad * 4;
#pragma unroll
        for (int r = 0; r < 4; ++r) {
            int row = rbase + r;
            if (row >= n_e) continue;
            int tok, slot; float wt;
            if (seg == NEXP) { tok = row; slot = 4; wt = 1.f; }
            else {
                int ent = lst[seg * T_TOK + row];
                tok = ent & 0xFFFF; slot = ent >> 16;
                wt = lstw[seg * T_TOK + row];
            }
            float* prow = P + ((size_t)slot * T_TOK + tok) * DIMD + n0 + wn + lrow;
#pragma unroll
            for (int j = 0; j < 4; ++j)
                prow[j * 16] = wt * acc[i][j][r];
        }
    }
}

// ---------- combine: y = P0+P1+P2+P3+P4 ----------
__global__ __launch_bounds__(256) void combine_kernel(
    const float4* __restrict__ P, float4* __restrict__ y)
{
    const int i = blockIdx.x * 256 + threadIdx.x;   // over T*D/4
    const size_t plane = (size_t)T_TOK * DIMD / 4;
    float4 a = P[i];
    float4 b = P[plane + i];
    float4 c = P[2 * plane + i];
    float4 d = P[3 * plane + i];
    float4 e = P[4 * plane + i];
    float4 o;
    o.x = a.x + b.x + c.x + d.x + e.x;
    o.y = a.y + b.y + c.y + d.y + e.y;
    o.z = a.z + b.z + c.z + d.z + e.z;
    o.w = a.w + b.w + c.w + d.w + e.w;
    y[i] = o;
}

// ---------- launcher ----------
extern "C" void kernel_launch(void* const* d_in, const int* in_sizes, int n_in,
                              void* d_out, int out_size, void* d_ws, size_t ws_size,
                              hipStream_t stream)
{
    const float* x   = (const float*)d_in[0];
    const float* gw  = (const float*)d_in[1];
    const float* gb  = (const float*)d_in[2];
    const float* w1  = (const float*)d_in[3];
    const float* w2  = (const float*)d_in[4];
    const float* w3  = (const float*)d_in[5];
    const float* ws1 = (const float*)d_in[6];
    const float* ws2 = (const float*)d_in[7];
    const float* ws3 = (const float*)d_in[8];

    char* base = (char*)d_ws;
    size_t off = 0;
    auto alloc = [&](size_t bytes) {
        char* q = base + off; off += (bytes + 255) & ~(size_t)255; return q;
    };
    unsigned short* xb   = (unsigned short*)alloc((size_t)T_TOK * DIMD * 2);
    unsigned short* w1b  = (unsigned short*)alloc((size_t)NEXP * INTERI * DIMD * 2);
    unsigned short* w3b  = (unsigned short*)alloc((size_t)NEXP * INTERI * DIMD * 2);
    unsigned short* ws1b = (unsigned short*)alloc((size_t)INTERI * DIMD * 2);
    unsigned short* ws3b = (unsigned short*)alloc((size_t)INTERI * DIMD * 2);
    unsigned short* Hb   = (unsigned short*)alloc((size_t)NSEG * T_TOK * INTERI * 2);
    int*            cnts = (int*)alloc(NEXP * 4);
    int*            lstp = (int*)alloc((size_t)NEXP * T_TOK * 4);
    float*          lstw = (float*)alloc((size_t)NEXP * T_TOK * 4);
    unsigned*       selp = (unsigned*)alloc((size_t)T_TOK * 4);
    float4*         selw = (float4*)alloc((size_t)T_TOK * 16);
    float*          Pb   = (float*)alloc((size_t)5 * T_TOK * DIMD * 4);

    // chunks: w1 1048576 + w3 1048576 + ws1 65536 + ws3 65536 = 2228224 -> 8704 blocks
    cvt_w_kernel<<<8704, 256, 0, stream>>>(w1, w3, ws1, ws3, w1b, w3b, ws1b, ws3b);
    gate_score_kernel<<<T_TOK / 4, 256, 0, stream>>>(x, gw, gb, selp, selw, xb);
    build_lists_kernel<<<NEXP, 256, 0, stream>>>(selp, selw, cnts, lstp, lstw);
    gemm1_kernel<<<1088, 256, 0, stream>>>(xb, w1b, w3b, ws1b, ws3b, cnts, lstp, Hb);
    gemm2_kernel<<<2176, 256, 0, stream>>>(Hb, w2, ws2, cnts, lstp, lstw, Pb);
    combine_kernel<<<(T_TOK * DIMD / 4) / 256, 256, 0, stream>>>((const float4*)Pb, (float4*)d_out);
}

// Round 8
// 242.350 us; speedup vs baseline: 1.3865x; 1.0503x over previous
//
#include <hip/hip_runtime.h>

#define T_TOK  2048
#define DIMD   1024
#define INTERI 512
#define NEXP   16
#define NSEG   17   // 16 routed + 1 shared (index 16)

typedef __bf16 bf16x8 __attribute__((ext_vector_type(8)));
typedef float  f32x4  __attribute__((ext_vector_type(4)));
typedef unsigned short u16x8 __attribute__((ext_vector_type(8)));

// XOR-swizzle (read side): chunk c (8 elems) of row r lives at slot (c + (r>>1)) & 3.
// Staging pre-swizzles the GLOBAL source per lane (m173 pattern):
// lane at slot s of row r fetches global chunk (s - (r>>1)) & 3, LDS dest linear.
#define SW(row, c) ((((c) + ((row) >> 1)) & 3) * 8)

// ---------- helpers ----------
__device__ __forceinline__ unsigned short f2b(float f) {
    union { float f; unsigned int u; } c; c.f = f;
    unsigned int u = c.u;
    unsigned int r = (u + 0x7FFFu + ((u >> 16) & 1u)) >> 16;  // RNE
    return (unsigned short)r;
}

// async global->LDS DMA, 16B per lane: dest = ldsbase + lane*16 (wave-uniform base)
__device__ __forceinline__ void glds16(const void* g, void* l) {
    __builtin_amdgcn_global_load_lds(
        (const __attribute__((address_space(1))) unsigned int*)g,
        (__attribute__((address_space(3))) unsigned int*)l,
        16, 0, 0);
}

// barrier that explicitly drains the DMA queue first (defensive)
__device__ __forceinline__ void dma_barrier() {
    asm volatile("s_waitcnt vmcnt(0)" ::: "memory");
    __syncthreads();
}

// ---------- prep: weight cvt (w1,w3,w2,ws1,ws3,ws2) + gate, ONE launch ----------
// blocks [0,6528): cvt, 16 floats/thread (4x float4 load, 2x 16B store)
// blocks [6528,7040): gate (one wave per token) + x->bf16
__global__ __launch_bounds__(256) void prep_kernel(
    const float* __restrict__ w1,  const float* __restrict__ w3,
    const float* __restrict__ w2,
    const float* __restrict__ ws1, const float* __restrict__ ws3,
    const float* __restrict__ ws2,
    unsigned short* __restrict__ w1b,  unsigned short* __restrict__ w3b,
    unsigned short* __restrict__ w2b,
    unsigned short* __restrict__ ws1b, unsigned short* __restrict__ ws3b,
    unsigned short* __restrict__ ws2b,
    const float* __restrict__ x, const float* __restrict__ gw,
    const float* __restrict__ gb,
    unsigned* __restrict__ sel, float4* __restrict__ selw,
    unsigned short* __restrict__ xb)
{
    const int b = blockIdx.x;
    if (b < 6528) {
        int g = b * 256 + threadIdx.x;    // chunk of 16 floats
        const float* s; unsigned short* d; int i;
        if      (g < 524288)  { s = w1;  d = w1b;  i = g; }
        else if (g < 1048576) { s = w3;  d = w3b;  i = g - 524288; }
        else if (g < 1572864) { s = w2;  d = w2b;  i = g - 1048576; }
        else if (g < 1605632) { s = ws1; d = ws1b; i = g - 1572864; }
        else if (g < 1638400) { s = ws3; d = ws3b; i = g - 1605632; }
        else                  { s = ws2; d = ws2b; i = g - 1638400; }
        float4 v0 = ((const float4*)s)[4 * i];
        float4 v1 = ((const float4*)s)[4 * i + 1];
        float4 v2 = ((const float4*)s)[4 * i + 2];
        float4 v3 = ((const float4*)s)[4 * i + 3];
        u16x8 o0, o1;
        o0[0] = f2b(v0.x); o0[1] = f2b(v0.y); o0[2] = f2b(v0.z); o0[3] = f2b(v0.w);
        o0[4] = f2b(v1.x); o0[5] = f2b(v1.y); o0[6] = f2b(v1.z); o0[7] = f2b(v1.w);
        o1[0] = f2b(v2.x); o1[1] = f2b(v2.y); o1[2] = f2b(v2.z); o1[3] = f2b(v2.w);
        o1[4] = f2b(v3.x); o1[5] = f2b(v3.y); o1[6] = f2b(v3.z); o1[7] = f2b(v3.w);
        ((u16x8*)d)[2 * i]     = o0;
        ((u16x8*)d)[2 * i + 1] = o1;
        return;
    }
    // ---- gate: scores + top-k selection + x->bf16 ----
    int tok  = (b - 6528) * 4 + (threadIdx.x >> 6);   // one wave per token
    int lane = threadIdx.x & 63;
    const float* xp = x + (size_t)tok * DIMD;
    float xv[16];
#pragma unroll
    for (int j = 0; j < 16; ++j) xv[j] = xp[j * 64 + lane];

    unsigned short* xbp = xb + (size_t)tok * DIMD;
#pragma unroll
    for (int j = 0; j < 16; ++j) xbp[j * 64 + lane] = f2b(xv[j]);

    float sc[16];
#pragma unroll
    for (int e = 0; e < 16; ++e) {
        const float* gwe = gw + e * DIMD;
        float p0 = 0.f, p1 = 0.f;
#pragma unroll
        for (int j = 0; j < 16; j += 2) {
            p0 += xv[j]     * gwe[j * 64 + lane];
            p1 += xv[j + 1] * gwe[(j + 1) * 64 + lane];
        }
        float p = p0 + p1;
#pragma unroll
        for (int o = 32; o; o >>= 1) p += __shfl_xor(p, o, 64);
        sc[e] = p;
    }
    if (lane != 0) return;

    float orig[16], s[16];
#pragma unroll
    for (int e = 0; e < 16; ++e) {
        orig[e] = 1.f / (1.f + expf(-sc[e]));
        s[e] = orig[e] + gb[e];
    }
    float gmax[4];
#pragma unroll
    for (int g = 0; g < 4; ++g) {
        float m = s[4 * g];
        for (int j = 1; j < 4; ++j) m = fmaxf(m, s[4 * g + j]);
        gmax[g] = m;
    }
    int g0 = 0;
    for (int g = 1; g < 4; ++g) if (gmax[g] > gmax[g0]) g0 = g;
    int g1 = -1;
    for (int g = 0; g < 4; ++g) { if (g == g0) continue; if (g1 < 0 || gmax[g] > gmax[g1]) g1 = g; }
    unsigned keep = (0xFu << (4 * g0)) | (0xFu << (4 * g1));
    unsigned used = 0;
    unsigned pk = 0;
    float w4[4];
    for (int j = 0; j < 4; ++j) {
        int best = -1;
        for (int e = 0; e < 16; ++e) {
            if (!((keep >> e) & 1u) || ((used >> e) & 1u)) continue;
            if (best < 0 || s[e] > s[best]) best = e;
        }
        used |= 1u << best;
        pk |= ((unsigned)best) << (4 * j);
        w4[j] = orig[best];
    }
    sel[tok] = pk;
    selw[tok] = make_float4(w4[0], w4[1], w4[2], w4[3]);
}

// ---------- gate phase 2: build per-expert token lists, NO atomics ----------
__global__ __launch_bounds__(256) void build_lists_kernel(
    const unsigned* __restrict__ sel, const float4* __restrict__ selw,
    int* __restrict__ counts, int* __restrict__ lst, float* __restrict__ lstw)
{
    const int e    = blockIdx.x;
    const int tid  = threadIdx.x;
    const int wave = tid >> 6;
    const int lane = tid & 63;

    __shared__ int wsum[4];
    __shared__ int basev;
    if (tid == 0) basev = 0;
    __syncthreads();

    for (int c = 0; c < T_TOK / 256; ++c) {
        int t = c * 256 + tid;
        unsigned s = sel[t];
        int match = -1;
#pragma unroll
        for (int j = 0; j < 4; ++j)
            if (((s >> (4 * j)) & 15u) == (unsigned)e) match = j;
        unsigned long long m = __ballot(match >= 0);
        int wpre = __popcll(m & ((1ull << lane) - 1ull));
        if (lane == 0) wsum[wave] = __popcll(m);
        __syncthreads();
        int pre = basev;
        for (int wv = 0; wv < wave; ++wv) pre += wsum[wv];
        if (match >= 0) {
            int pos = pre + wpre;
            lst [e * T_TOK + pos] = t | (match << 16);
            const float* wp = (const float*)&selw[t];
            lstw[e * T_TOK + pos] = wp[match];
        }
        __syncthreads();
        if (tid == 0) basev += wsum[0] + wsum[1] + wsum[2] + wsum[3];
        __syncthreads();
    }
    if (tid == 0) counts[e] = basev;
}

// ---------- GEMM1: H = silu(X W1^T) * (X W3^T) ----------
// 128x128 tile, wave tile 64x64 (dual h1/h3), BK=64.
// Staging via global_load_lds DMA (pre-swizzled global source, linear LDS dest).
// Per K-step: 12 DMA issues -> vmcnt(0)+sync -> ds_read+MFMA -> sync.
// grid: 1024 routed + 64 shared = 1088.
__global__ __launch_bounds__(256, 2) void gemm1_kernel(
    const unsigned short* __restrict__ xb,
    const unsigned short* __restrict__ w1b,
    const unsigned short* __restrict__ w3b,
    const unsigned short* __restrict__ ws1b,
    const unsigned short* __restrict__ ws3b,
    const int* __restrict__ counts,
    const int* __restrict__ lst,
    unsigned short* __restrict__ H)
{
    int b = blockIdx.x;
    int seg, mt, nt;
    if (b < 1024) {
        int xcd = b & 7, slot = b >> 3;     // slot 0..127
        seg = xcd + 8 * (slot >> 6);        // 2 experts per XCD
        int tile = slot & 63;
        mt = tile >> 2; nt = tile & 3;      // mt 0..15, nt 0..3
    } else {
        seg = NEXP;
        int tile = b - 1024;                // 0..63
        mt = tile >> 2; nt = tile & 3;
    }
    const int n_e = (seg == NEXP) ? T_TOK : counts[seg];
    const int m0  = mt * 128;
    if (m0 >= n_e) return;
    const int n0  = nt * 128;

    const unsigned short* w1p = (seg == NEXP) ? ws1b : w1b + (size_t)seg * INTERI * DIMD;
    const unsigned short* w3p = (seg == NEXP) ? ws3b : w3b + (size_t)seg * INTERI * DIMD;
    const int* lste = lst + seg * T_TOK;

    __shared__ __align__(16) unsigned short lA [2][128][32];   // 16 KB (kk-halves)
    __shared__ __align__(16) unsigned short lB1[2][128][32];   // 16 KB
    __shared__ __align__(16) unsigned short lB3[2][128][32];   // 16 KB

    const int tid  = threadIdx.x;
    const int wave = tid >> 6;
    const int lane = tid & 63;
    const int quad = lane >> 4;
    const int lrow = lane & 15;

    // DMA staging geometry: wave covers rows wave*32 + (lane>>2) (+16)
    const int lr  = lane >> 2;
    const int lsl = lane & 3;
    const int r0  = wave * 32 + lr, r1 = r0 + 16;
    const int c0  = (lsl - (r0 >> 1)) & 3;     // global chunk for slot lsl
    const int c1  = (lsl - (r1 >> 1)) & 3;
    int ga0 = m0 + r0; if (ga0 > n_e - 1) ga0 = n_e - 1;
    int ga1 = m0 + r1; if (ga1 > n_e - 1) ga1 = n_e - 1;
    const int tA0 = (seg == NEXP) ? ga0 : (lste[ga0] & 0xFFFF);
    const int tA1 = (seg == NEXP) ? ga1 : (lste[ga1] & 0xFFFF);
    const unsigned short* pA0  = xb  + (size_t)tA0 * DIMD + c0 * 8;
    const unsigned short* pA1  = xb  + (size_t)tA1 * DIMD + c1 * 8;
    const unsigned short* pB10 = w1p + (size_t)(n0 + r0) * DIMD + c0 * 8;
    const unsigned short* pB11 = w1p + (size_t)(n0 + r1) * DIMD + c1 * 8;
    const unsigned short* pB30 = w3p + (size_t)(n0 + r0) * DIMD + c0 * 8;
    const unsigned short* pB31 = w3p + (size_t)(n0 + r1) * DIMD + c1 * 8;

#define G1STAGE(k0) do { \
    glds16(pA0  + (k0),      &lA [0][wave * 32][0]); \
    glds16(pA0  + (k0) + 32, &lA [1][wave * 32][0]); \
    glds16(pA1  + (k0),      &lA [0][wave * 32 + 16][0]); \
    glds16(pA1  + (k0) + 32, &lA [1][wave * 32 + 16][0]); \
    glds16(pB10 + (k0),      &lB1[0][wave * 32][0]); \
    glds16(pB10 + (k0) + 32, &lB1[1][wave * 32][0]); \
    glds16(pB11 + (k0),      &lB1[0][wave * 32 + 16][0]); \
    glds16(pB11 + (k0) + 32, &lB1[1][wave * 32 + 16][0]); \
    glds16(pB30 + (k0),      &lB3[0][wave * 32][0]); \
    glds16(pB30 + (k0) + 32, &lB3[1][wave * 32][0]); \
    glds16(pB31 + (k0),      &lB3[0][wave * 32 + 16][0]); \
    glds16(pB31 + (k0) + 32, &lB3[1][wave * 32 + 16][0]); \
} while (0)

    f32x4 acc1[4][4], acc3[4][4];
    const f32x4 zero = {0.f, 0.f, 0.f, 0.f};
#pragma unroll
    for (int i = 0; i < 4; ++i)
#pragma unroll
        for (int j = 0; j < 4; ++j) { acc1[i][j] = zero; acc3[i][j] = zero; }

    const int wm = (wave & 1) * 64;
    const int wn = (wave >> 1) * 64;

    const int NK = DIMD / 64;  // 16
    for (int it = 0; it < NK; ++it) {
        G1STAGE(it * 64);
        dma_barrier();                     // DMA drained: tile in LDS
#pragma unroll
        for (int kk = 0; kk < 2; ++kk) {
            bf16x8 a[4], bv[4];
#pragma unroll
            for (int t = 0; t < 4; ++t) {
                int rr = wm + t * 16 + lrow;
                a[t] = *(const bf16x8*)&lA[kk][rr][SW(rr, quad)];
            }
#pragma unroll
            for (int t = 0; t < 4; ++t) {
                int rc = wn + t * 16 + lrow;
                bv[t] = *(const bf16x8*)&lB1[kk][rc][SW(rc, quad)];
            }
#pragma unroll
            for (int i = 0; i < 4; ++i)
#pragma unroll
                for (int j = 0; j < 4; ++j)
                    acc1[i][j] = __builtin_amdgcn_mfma_f32_16x16x32_bf16(a[i], bv[j], acc1[i][j], 0, 0, 0);
#pragma unroll
            for (int t = 0; t < 4; ++t) {
                int rc = wn + t * 16 + lrow;
                bv[t] = *(const bf16x8*)&lB3[kk][rc][SW(rc, quad)];
            }
#pragma unroll
            for (int i = 0; i < 4; ++i)
#pragma unroll
                for (int j = 0; j < 4; ++j)
                    acc3[i][j] = __builtin_amdgcn_mfma_f32_16x16x32_bf16(a[i], bv[j], acc3[i][j], 0, 0, 0);
        }
        __syncthreads();                   // LDS reads done before next DMA overwrite
    }
#undef G1STAGE

    unsigned short* Hseg = H + (size_t)seg * T_TOK * INTERI;
#pragma unroll
    for (int i = 0; i < 4; ++i) {
        int rbase = m0 + wm + i * 16 + quad * 4;
#pragma unroll
        for (int r = 0; r < 4; ++r) {
            int row = rbase + r;
            if (row >= n_e) continue;
            unsigned short* hrow = Hseg + (size_t)row * INTERI + n0 + wn + lrow;
#pragma unroll
            for (int j = 0; j < 4; ++j) {
                float v1 = acc1[i][j][r];
                float v3 = acc3[i][j][r];
                float hv = (v1 / (1.f + __expf(-v1))) * v3;   // silu(v1)*v3
                hrow[j * 16] = f2b(hv);
            }
        }
    }
}

// ---------- GEMM2: P[slot] = w * (H W2^T), 128x128 tile, atomic-free ----------
// All-bf16; staging via global_load_lds DMA (8 issues/K-step).
// grid: 2048 routed slots + 128 shared = 2176.
__global__ __launch_bounds__(256, 2) void gemm2_kernel(
    const unsigned short* __restrict__ H,
    const unsigned short* __restrict__ w2b,
    const unsigned short* __restrict__ ws2b,
    const int* __restrict__ counts,
    const int* __restrict__ lst,
    const float* __restrict__ lstw,
    float* __restrict__ P)
{
    int b = blockIdx.x;
    int seg, mt, nt;
    if (b < 2048) {
        int xcd = b & 7, slot = b >> 3;     // 0..255
        seg = xcd + 8 * (slot >> 7);
        int tile = slot & 127;
        mt = tile >> 3; nt = tile & 7;      // mt 0..15, nt 0..7
    } else {
        seg = NEXP;
        int tile = b - 2048;                // 0..127
        mt = tile >> 3; nt = tile & 7;
    }
    const int n_e = (seg == NEXP) ? T_TOK : counts[seg];
    const int m0  = mt * 128;
    if (m0 >= n_e) return;
    const int n0  = nt * 128;

    const unsigned short* w2p  = (seg == NEXP) ? ws2b : w2b + (size_t)seg * DIMD * INTERI;
    const unsigned short* Hseg = H + (size_t)seg * T_TOK * INTERI;

    __shared__ __align__(16) unsigned short lA[2][128][32];   // 16 KB
    __shared__ __align__(16) unsigned short lB[2][128][32];   // 16 KB

    const int tid  = threadIdx.x;
    const int wave = tid >> 6;
    const int lane = tid & 63;
    const int quad = lane >> 4;
    const int lrow = lane & 15;

    const int lr  = lane >> 2;
    const int lsl = lane & 3;
    const int r0  = wave * 32 + lr, r1 = r0 + 16;
    const int c0  = (lsl - (r0 >> 1)) & 3;
    const int c1  = (lsl - (r1 >> 1)) & 3;
    int ga0 = m0 + r0; if (ga0 > n_e - 1) ga0 = n_e - 1;
    int ga1 = m0 + r1; if (ga1 > n_e - 1) ga1 = n_e - 1;
    const unsigned short* pA0 = Hseg + (size_t)ga0 * INTERI + c0 * 8;
    const unsigned short* pA1 = Hseg + (size_t)ga1 * INTERI + c1 * 8;
    const unsigned short* pB0 = w2p + (size_t)(n0 + r0) * INTERI + c0 * 8;
    const unsigned short* pB1 = w2p + (size_t)(n0 + r1) * INTERI + c1 * 8;

#define G2STAGE(k0) do { \
    glds16(pA0 + (k0),      &lA[0][wave * 32][0]); \
    glds16(pA0 + (k0) + 32, &lA[1][wave * 32][0]); \
    glds16(pA1 + (k0),      &lA[0][wave * 32 + 16][0]); \
    glds16(pA1 + (k0) + 32, &lA[1][wave * 32 + 16][0]); \
    glds16(pB0 + (k0),      &lB[0][wave * 32][0]); \
    glds16(pB0 + (k0) + 32, &lB[1][wave * 32][0]); \
    glds16(pB1 + (k0),      &lB[0][wave * 32 + 16][0]); \
    glds16(pB1 + (k0) + 32, &lB[1][wave * 32 + 16][0]); \
} while (0)

    f32x4 acc[4][4];
    const f32x4 zero = {0.f, 0.f, 0.f, 0.f};
#pragma unroll
    for (int i = 0; i < 4; ++i)
#pragma unroll
        for (int j = 0; j < 4; ++j) acc[i][j] = zero;

    const int wm = (wave & 1) * 64;
    const int wn = (wave >> 1) * 64;

    const int NK = INTERI / 64;  // 8
    for (int it = 0; it < NK; ++it) {
        G2STAGE(it * 64);
        dma_barrier();
#pragma unroll
        for (int kk = 0; kk < 2; ++kk) {
            bf16x8 a[4], bv[4];
#pragma unroll
            for (int t = 0; t < 4; ++t) {
                int rr = wm + t * 16 + lrow;
                a[t] = *(const bf16x8*)&lA[kk][rr][SW(rr, quad)];
            }
#pragma unroll
            for (int t = 0; t < 4; ++t) {
                int rc = wn + t * 16 + lrow;
                bv[t] = *(const bf16x8*)&lB[kk][rc][SW(rc, quad)];
            }
#pragma unroll
            for (int i = 0; i < 4; ++i)
#pragma unroll
                for (int j = 0; j < 4; ++j)
                    acc[i][j] = __builtin_amdgcn_mfma_f32_16x16x32_bf16(a[i], bv[j], acc[i][j], 0, 0, 0);
        }
        __syncthreads();
    }
#undef G2STAGE

#pragma unroll
    for (int i = 0; i < 4; ++i) {
        int rbase = m0 + wm + i * 16 + quad * 4;
#pragma unroll
        for (int r = 0; r < 4; ++r) {
            int row = rbase + r;
            if (row >= n_e) continue;
            int tok, slot; float wt;
            if (seg == NEXP) { tok = row; slot = 4; wt = 1.f; }
            else {
                int ent = lst[seg * T_TOK + row];
                tok = ent & 0xFFFF; slot = ent >> 16;
                wt = lstw[seg * T_TOK + row];
            }
            float* prow = P + ((size_t)slot * T_TOK + tok) * DIMD + n0 + wn + lrow;
#pragma unroll
            for (int j = 0; j < 4; ++j)
                prow[j * 16] = wt * acc[i][j][r];
        }
    }
}

// ---------- combine: y = P0+P1+P2+P3+P4 ----------
__global__ __launch_bounds__(256) void combine_kernel(
    const float4* __restrict__ P, float4* __restrict__ y)
{
    const int i = blockIdx.x * 256 + threadIdx.x;   // over T*D/4
    const size_t plane = (size_t)T_TOK * DIMD / 4;
    float4 a = P[i];
    float4 b = P[plane + i];
    float4 c = P[2 * plane + i];
    float4 d = P[3 * plane + i];
    float4 e = P[4 * plane + i];
    float4 o;
    o.x = a.x + b.x + c.x + d.x + e.x;
    o.y = a.y + b.y + c.y + d.y + e.y;
    o.z = a.z + b.z + c.z + d.z + e.z;
    o.w = a.w + b.w + c.w + d.w + e.w;
    y[i] = o;
}

// ---------- launcher ----------
extern "C" void kernel_launch(void* const* d_in, const int* in_sizes, int n_in,
                              void* d_out, int out_size, void* d_ws, size_t ws_size,
                              hipStream_t stream)
{
    const float* x   = (const float*)d_in[0];
    const float* gw  = (const float*)d_in[1];
    const float* gb  = (const float*)d_in[2];
    const float* w1  = (const float*)d_in[3];
    const float* w2  = (const float*)d_in[4];
    const float* w3  = (const float*)d_in[5];
    const float* ws1 = (const float*)d_in[6];
    const float* ws2 = (const float*)d_in[7];
    const float* ws3 = (const float*)d_in[8];

    char* base = (char*)d_ws;
    size_t off = 0;
    auto alloc = [&](size_t bytes) {
        char* q = base + off; off += (bytes + 255) & ~(size_t)255; return q;
    };
    unsigned short* xb   = (unsigned short*)alloc((size_t)T_TOK * DIMD * 2);
    unsigned short* w1b  = (unsigned short*)alloc((size_t)NEXP * INTERI * DIMD * 2);
    unsigned short* w3b  = (unsigned short*)alloc((size_t)NEXP * INTERI * DIMD * 2);
    unsigned short* w2b  = (unsigned short*)alloc((size_t)NEXP * DIMD * INTERI * 2);
    unsigned short* ws1b = (unsigned short*)alloc((size_t)INTERI * DIMD * 2);
    unsigned short* ws3b = (unsigned short*)alloc((size_t)INTERI * DIMD * 2);
    unsigned short* ws2b = (unsigned short*)alloc((size_t)DIMD * INTERI * 2);
    unsigned short* Hb   = (unsigned short*)alloc((size_t)NSEG * T_TOK * INTERI * 2);
    int*            cnts = (int*)alloc(NEXP * 4);
    int*            lstp = (int*)alloc((size_t)NEXP * T_TOK * 4);
    float*          lstw = (float*)alloc((size_t)NEXP * T_TOK * 4);
    unsigned*       selp = (unsigned*)alloc((size_t)T_TOK * 4);
    float4*         selw = (float4*)alloc((size_t)T_TOK * 16);
    float*          Pb   = (float*)alloc((size_t)5 * T_TOK * DIMD * 4);

    // prep grid: 6528 cvt blocks (16 floats/thread) + 512 gate blocks
    prep_kernel<<<7040, 256, 0, stream>>>(w1, w3, w2, ws1, ws3, ws2,
                                          w1b, w3b, w2b, ws1b, ws3b, ws2b,
                                          x, gw, gb, selp, selw, xb);
    build_lists_kernel<<<NEXP, 256, 0, stream>>>(selp, selw, cnts, lstp, lstw);
    gemm1_kernel<<<1088, 256, 0, stream>>>(xb, w1b, w3b, ws1b, ws3b, cnts, lstp, Hb);
    gemm2_kernel<<<2176, 256, 0, stream>>>(Hb, w2b, ws2b, cnts, lstp, lstw, Pb);
    combine_kernel<<<(T_TOK * DIMD / 4) / 256, 256, 0, stream>>>((const float4*)Pb, (float4*)d_out);
}

// Round 9
// 233.355 us; speedup vs baseline: 1.4400x; 1.0385x over previous
//
#include <hip/hip_runtime.h>

#define T_TOK  2048
#define DIMD   1024
#define INTERI 512
#define NEXP   16
#define NSEG   17   // 16 routed + 1 shared (index 16)

typedef __bf16 bf16x8 __attribute__((ext_vector_type(8)));
typedef float  f32x4  __attribute__((ext_vector_type(4)));
typedef unsigned short u16x8 __attribute__((ext_vector_type(8)));

// XOR-swizzle (read side): chunk c (8 elems) of row r lives at slot (c + (r>>1)) & 3.
// Staging pre-swizzles the GLOBAL source per lane (m173 pattern):
// lane at slot s of row r fetches global chunk (s - (r>>1)) & 3, LDS dest linear.
#define SW(row, c) ((((c) + ((row) >> 1)) & 3) * 8)

// ---------- helpers ----------
__device__ __forceinline__ unsigned short f2b(float f) {
    union { float f; unsigned int u; } c; c.f = f;
    unsigned int u = c.u;
    unsigned int r = (u + 0x7FFFu + ((u >> 16) & 1u)) >> 16;  // RNE
    return (unsigned short)r;
}

// async global->LDS DMA, 16B per lane: dest = ldsbase + lane*16 (wave-uniform base)
__device__ __forceinline__ void glds16(const void* g, void* l) {
    __builtin_amdgcn_global_load_lds(
        (const __attribute__((address_space(1))) unsigned int*)g,
        (__attribute__((address_space(3))) unsigned int*)l,
        16, 0, 0);
}

// barrier that explicitly drains the DMA queue first (defensive)
__device__ __forceinline__ void dma_barrier() {
    asm volatile("s_waitcnt vmcnt(0)" ::: "memory");
    __syncthreads();
}

// ---------- prep: gate FIRST, then weight cvt, ONE launch ----------
// blocks [0,512): gate (one wave per token) + x->bf16   <- long blocks start at t=0
// blocks [512,7040): cvt, 16 floats/thread (4x float4 NT load, 2x 16B store)
__global__ __launch_bounds__(256) void prep_kernel(
    const float* __restrict__ w1,  const float* __restrict__ w3,
    const float* __restrict__ w2,
    const float* __restrict__ ws1, const float* __restrict__ ws3,
    const float* __restrict__ ws2,
    unsigned short* __restrict__ w1b,  unsigned short* __restrict__ w3b,
    unsigned short* __restrict__ w2b,
    unsigned short* __restrict__ ws1b, unsigned short* __restrict__ ws3b,
    unsigned short* __restrict__ ws2b,
    const float* __restrict__ x, const float* __restrict__ gw,
    const float* __restrict__ gb,
    unsigned* __restrict__ sel, float4* __restrict__ selw,
    unsigned short* __restrict__ xb)
{
    const int b = blockIdx.x;
    if (b >= 512) {
        // ---- weight conversion (read-once fp32: non-temporal loads) ----
        int g = (b - 512) * 256 + threadIdx.x;    // chunk of 16 floats
        const float* s; unsigned short* d; int i;
        if      (g < 524288)  { s = w1;  d = w1b;  i = g; }
        else if (g < 1048576) { s = w3;  d = w3b;  i = g - 524288; }
        else if (g < 1572864) { s = w2;  d = w2b;  i = g - 1048576; }
        else if (g < 1605632) { s = ws1; d = ws1b; i = g - 1572864; }
        else if (g < 1638400) { s = ws3; d = ws3b; i = g - 1605632; }
        else                  { s = ws2; d = ws2b; i = g - 1638400; }
        const f32x4* sp = (const f32x4*)s;
        f32x4 v0 = __builtin_nontemporal_load(&sp[4 * i]);
        f32x4 v1 = __builtin_nontemporal_load(&sp[4 * i + 1]);
        f32x4 v2 = __builtin_nontemporal_load(&sp[4 * i + 2]);
        f32x4 v3 = __builtin_nontemporal_load(&sp[4 * i + 3]);
        u16x8 o0, o1;
        o0[0] = f2b(v0[0]); o0[1] = f2b(v0[1]); o0[2] = f2b(v0[2]); o0[3] = f2b(v0[3]);
        o0[4] = f2b(v1[0]); o0[5] = f2b(v1[1]); o0[6] = f2b(v1[2]); o0[7] = f2b(v1[3]);
        o1[0] = f2b(v2[0]); o1[1] = f2b(v2[1]); o1[2] = f2b(v2[2]); o1[3] = f2b(v2[3]);
        o1[4] = f2b(v3[0]); o1[5] = f2b(v3[1]); o1[6] = f2b(v3[2]); o1[7] = f2b(v3[3]);
        ((u16x8*)d)[2 * i]     = o0;
        ((u16x8*)d)[2 * i + 1] = o1;
        return;
    }
    // ---- gate: scores + top-k selection + x->bf16 ----
    int tok  = b * 4 + (threadIdx.x >> 6);   // one wave per token
    int lane = threadIdx.x & 63;
    const float* xp = x + (size_t)tok * DIMD;
    float xv[16];
#pragma unroll
    for (int j = 0; j < 16; ++j) xv[j] = xp[j * 64 + lane];

    unsigned short* xbp = xb + (size_t)tok * DIMD;
#pragma unroll
    for (int j = 0; j < 16; ++j) xbp[j * 64 + lane] = f2b(xv[j]);

    float sc[16];
#pragma unroll
    for (int e = 0; e < 16; ++e) {
        const float* gwe = gw + e * DIMD;
        float p0 = 0.f, p1 = 0.f;
#pragma unroll
        for (int j = 0; j < 16; j += 2) {
            p0 += xv[j]     * gwe[j * 64 + lane];
            p1 += xv[j + 1] * gwe[(j + 1) * 64 + lane];
        }
        float p = p0 + p1;
#pragma unroll
        for (int o = 32; o; o >>= 1) p += __shfl_xor(p, o, 64);
        sc[e] = p;
    }
    if (lane != 0) return;

    float orig[16], s[16];
#pragma unroll
    for (int e = 0; e < 16; ++e) {
        orig[e] = 1.f / (1.f + expf(-sc[e]));
        s[e] = orig[e] + gb[e];
    }
    float gmax[4];
#pragma unroll
    for (int g = 0; g < 4; ++g) {
        float m = s[4 * g];
        for (int j = 1; j < 4; ++j) m = fmaxf(m, s[4 * g + j]);
        gmax[g] = m;
    }
    int g0 = 0;
    for (int g = 1; g < 4; ++g) if (gmax[g] > gmax[g0]) g0 = g;
    int g1 = -1;
    for (int g = 0; g < 4; ++g) { if (g == g0) continue; if (g1 < 0 || gmax[g] > gmax[g1]) g1 = g; }
    unsigned keep = (0xFu << (4 * g0)) | (0xFu << (4 * g1));
    unsigned used = 0;
    unsigned pk = 0;
    float w4[4];
    for (int j = 0; j < 4; ++j) {
        int best = -1;
        for (int e = 0; e < 16; ++e) {
            if (!((keep >> e) & 1u) || ((used >> e) & 1u)) continue;
            if (best < 0 || s[e] > s[best]) best = e;
        }
        used |= 1u << best;
        pk |= ((unsigned)best) << (4 * j);
        w4[j] = orig[best];
    }
    sel[tok] = pk;
    selw[tok] = make_float4(w4[0], w4[1], w4[2], w4[3]);
}

// ---------- gate phase 2: build per-expert token lists, NO atomics ----------
__global__ __launch_bounds__(256) void build_lists_kernel(
    const unsigned* __restrict__ sel, const float4* __restrict__ selw,
    int* __restrict__ counts, int* __restrict__ lst, float* __restrict__ lstw)
{
    const int e    = blockIdx.x;
    const int tid  = threadIdx.x;
    const int wave = tid >> 6;
    const int lane = tid & 63;

    __shared__ int wsum[4];
    __shared__ int basev;
    if (tid == 0) basev = 0;
    __syncthreads();

    for (int c = 0; c < T_TOK / 256; ++c) {
        int t = c * 256 + tid;
        unsigned s = sel[t];
        int match = -1;
#pragma unroll
        for (int j = 0; j < 4; ++j)
            if (((s >> (4 * j)) & 15u) == (unsigned)e) match = j;
        unsigned long long m = __ballot(match >= 0);
        int wpre = __popcll(m & ((1ull << lane) - 1ull));
        if (lane == 0) wsum[wave] = __popcll(m);
        __syncthreads();
        int pre = basev;
        for (int wv = 0; wv < wave; ++wv) pre += wsum[wv];
        if (match >= 0) {
            int pos = pre + wpre;
            lst [e * T_TOK + pos] = t | (match << 16);
            const float* wp = (const float*)&selw[t];
            lstw[e * T_TOK + pos] = wp[match];
        }
        __syncthreads();
        if (tid == 0) basev += wsum[0] + wsum[1] + wsum[2] + wsum[3];
        __syncthreads();
    }
    if (tid == 0) counts[e] = basev;
}

// ---------- GEMM1: H = silu(X W1^T) * (X W3^T) ----------
// 128x128 tile, wave tile 64x64 (dual h1/h3), BK=64.
// Staging via global_load_lds DMA (pre-swizzled global source, linear LDS dest).
// Per K-step: 12 DMA issues -> vmcnt(0)+sync -> ds_read+MFMA -> sync.
// grid: 1024 routed + 64 shared = 1088.
__global__ __launch_bounds__(256, 2) void gemm1_kernel(
    const unsigned short* __restrict__ xb,
    const unsigned short* __restrict__ w1b,
    const unsigned short* __restrict__ w3b,
    const unsigned short* __restrict__ ws1b,
    const unsigned short* __restrict__ ws3b,
    const int* __restrict__ counts,
    const int* __restrict__ lst,
    unsigned short* __restrict__ H)
{
    int b = blockIdx.x;
    int seg, mt, nt;
    if (b < 1024) {
        int xcd = b & 7, slot = b >> 3;     // slot 0..127
        seg = xcd + 8 * (slot >> 6);        // 2 experts per XCD
        int tile = slot & 63;
        mt = tile >> 2; nt = tile & 3;      // mt 0..15, nt 0..3
    } else {
        seg = NEXP;
        int tile = b - 1024;                // 0..63
        mt = tile >> 2; nt = tile & 3;
    }
    const int n_e = (seg == NEXP) ? T_TOK : counts[seg];
    const int m0  = mt * 128;
    if (m0 >= n_e) return;
    const int n0  = nt * 128;

    const unsigned short* w1p = (seg == NEXP) ? ws1b : w1b + (size_t)seg * INTERI * DIMD;
    const unsigned short* w3p = (seg == NEXP) ? ws3b : w3b + (size_t)seg * INTERI * DIMD;
    const int* lste = lst + seg * T_TOK;

    __shared__ __align__(16) unsigned short lA [2][128][32];   // 16 KB (kk-halves)
    __shared__ __align__(16) unsigned short lB1[2][128][32];   // 16 KB
    __shared__ __align__(16) unsigned short lB3[2][128][32];   // 16 KB

    const int tid  = threadIdx.x;
    const int wave = tid >> 6;
    const int lane = tid & 63;
    const int quad = lane >> 4;
    const int lrow = lane & 15;

    // DMA staging geometry: wave covers rows wave*32 + (lane>>2) (+16)
    const int lr  = lane >> 2;
    const int lsl = lane & 3;
    const int r0  = wave * 32 + lr, r1 = r0 + 16;
    const int c0  = (lsl - (r0 >> 1)) & 3;     // global chunk for slot lsl
    const int c1  = (lsl - (r1 >> 1)) & 3;
    int ga0 = m0 + r0; if (ga0 > n_e - 1) ga0 = n_e - 1;
    int ga1 = m0 + r1; if (ga1 > n_e - 1) ga1 = n_e - 1;
    const int tA0 = (seg == NEXP) ? ga0 : (lste[ga0] & 0xFFFF);
    const int tA1 = (seg == NEXP) ? ga1 : (lste[ga1] & 0xFFFF);
    const unsigned short* pA0  = xb  + (size_t)tA0 * DIMD + c0 * 8;
    const unsigned short* pA1  = xb  + (size_t)tA1 * DIMD + c1 * 8;
    const unsigned short* pB10 = w1p + (size_t)(n0 + r0) * DIMD + c0 * 8;
    const unsigned short* pB11 = w1p + (size_t)(n0 + r1) * DIMD + c1 * 8;
    const unsigned short* pB30 = w3p + (size_t)(n0 + r0) * DIMD + c0 * 8;
    const unsigned short* pB31 = w3p + (size_t)(n0 + r1) * DIMD + c1 * 8;

#define G1STAGE(k0) do { \
    glds16(pA0  + (k0),      &lA [0][wave * 32][0]); \
    glds16(pA0  + (k0) + 32, &lA [1][wave * 32][0]); \
    glds16(pA1  + (k0),      &lA [0][wave * 32 + 16][0]); \
    glds16(pA1  + (k0) + 32, &lA [1][wave * 32 + 16][0]); \
    glds16(pB10 + (k0),      &lB1[0][wave * 32][0]); \
    glds16(pB10 + (k0) + 32, &lB1[1][wave * 32][0]); \
    glds16(pB11 + (k0),      &lB1[0][wave * 32 + 16][0]); \
    glds16(pB11 + (k0) + 32, &lB1[1][wave * 32 + 16][0]); \
    glds16(pB30 + (k0),      &lB3[0][wave * 32][0]); \
    glds16(pB30 + (k0) + 32, &lB3[1][wave * 32][0]); \
    glds16(pB31 + (k0),      &lB3[0][wave * 32 + 16][0]); \
    glds16(pB31 + (k0) + 32, &lB3[1][wave * 32 + 16][0]); \
} while (0)

    f32x4 acc1[4][4], acc3[4][4];
    const f32x4 zero = {0.f, 0.f, 0.f, 0.f};
#pragma unroll
    for (int i = 0; i < 4; ++i)
#pragma unroll
        for (int j = 0; j < 4; ++j) { acc1[i][j] = zero; acc3[i][j] = zero; }

    const int wm = (wave & 1) * 64;
    const int wn = (wave >> 1) * 64;

    const int NK = DIMD / 64;  // 16
    for (int it = 0; it < NK; ++it) {
        G1STAGE(it * 64);
        dma_barrier();                     // DMA drained: tile in LDS
#pragma unroll
        for (int kk = 0; kk < 2; ++kk) {
            bf16x8 a[4], bv[4];
#pragma unroll
            for (int t = 0; t < 4; ++t) {
                int rr = wm + t * 16 + lrow;
                a[t] = *(const bf16x8*)&lA[kk][rr][SW(rr, quad)];
            }
#pragma unroll
            for (int t = 0; t < 4; ++t) {
                int rc = wn + t * 16 + lrow;
                bv[t] = *(const bf16x8*)&lB1[kk][rc][SW(rc, quad)];
            }
#pragma unroll
            for (int i = 0; i < 4; ++i)
#pragma unroll
                for (int j = 0; j < 4; ++j)
                    acc1[i][j] = __builtin_amdgcn_mfma_f32_16x16x32_bf16(a[i], bv[j], acc1[i][j], 0, 0, 0);
#pragma unroll
            for (int t = 0; t < 4; ++t) {
                int rc = wn + t * 16 + lrow;
                bv[t] = *(const bf16x8*)&lB3[kk][rc][SW(rc, quad)];
            }
#pragma unroll
            for (int i = 0; i < 4; ++i)
#pragma unroll
                for (int j = 0; j < 4; ++j)
                    acc3[i][j] = __builtin_amdgcn_mfma_f32_16x16x32_bf16(a[i], bv[j], acc3[i][j], 0, 0, 0);
        }
        __syncthreads();                   // LDS reads done before next DMA overwrite
    }
#undef G1STAGE

    unsigned short* Hseg = H + (size_t)seg * T_TOK * INTERI;
#pragma unroll
    for (int i = 0; i < 4; ++i) {
        int rbase = m0 + wm + i * 16 + quad * 4;
#pragma unroll
        for (int r = 0; r < 4; ++r) {
            int row = rbase + r;
            if (row >= n_e) continue;
            unsigned short* hrow = Hseg + (size_t)row * INTERI + n0 + wn + lrow;
#pragma unroll
            for (int j = 0; j < 4; ++j) {
                float v1 = acc1[i][j][r];
                float v3 = acc3[i][j][r];
                float hv = (v1 / (1.f + __expf(-v1))) * v3;   // silu(v1)*v3
                hrow[j * 16] = f2b(hv);
            }
        }
    }
}

// ---------- GEMM2: P[slot] = w * (H W2^T), 128x128 tile, atomic-free ----------
// All-bf16; staging via global_load_lds DMA (8 issues/K-step).
// grid: 2048 routed slots + 128 shared = 2176.
__global__ __launch_bounds__(256, 2) void gemm2_kernel(
    const unsigned short* __restrict__ H,
    const unsigned short* __restrict__ w2b,
    const unsigned short* __restrict__ ws2b,
    const int* __restrict__ counts,
    const int* __restrict__ lst,
    const float* __restrict__ lstw,
    float* __restrict__ P)
{
    int b = blockIdx.x;
    int seg, mt, nt;
    if (b < 2048) {
        int xcd = b & 7, slot = b >> 3;     // 0..255
        seg = xcd + 8 * (slot >> 7);
        int tile = slot & 127;
        mt = tile >> 3; nt = tile & 7;      // mt 0..15, nt 0..7
    } else {
        seg = NEXP;
        int tile = b - 2048;                // 0..127
        mt = tile >> 3; nt = tile & 7;
    }
    const int n_e = (seg == NEXP) ? T_TOK : counts[seg];
    const int m0  = mt * 128;
    if (m0 >= n_e) return;
    const int n0  = nt * 128;

    const unsigned short* w2p  = (seg == NEXP) ? ws2b : w2b + (size_t)seg * DIMD * INTERI;
    const unsigned short* Hseg = H + (size_t)seg * T_TOK * INTERI;

    __shared__ __align__(16) unsigned short lA[2][128][32];   // 16 KB
    __shared__ __align__(16) unsigned short lB[2][128][32];   // 16 KB

    const int tid  = threadIdx.x;
    const int wave = tid >> 6;
    const int lane = tid & 63;
    const int quad = lane >> 4;
    const int lrow = lane & 15;

    const int lr  = lane >> 2;
    const int lsl = lane & 3;
    const int r0  = wave * 32 + lr, r1 = r0 + 16;
    const int c0  = (lsl - (r0 >> 1)) & 3;
    const int c1  = (lsl - (r1 >> 1)) & 3;
    int ga0 = m0 + r0; if (ga0 > n_e - 1) ga0 = n_e - 1;
    int ga1 = m0 + r1; if (ga1 > n_e - 1) ga1 = n_e - 1;
    const unsigned short* pA0 = Hseg + (size_t)ga0 * INTERI + c0 * 8;
    const unsigned short* pA1 = Hseg + (size_t)ga1 * INTERI + c1 * 8;
    const unsigned short* pB0 = w2p + (size_t)(n0 + r0) * INTERI + c0 * 8;
    const unsigned short* pB1 = w2p + (size_t)(n0 + r1) * INTERI + c1 * 8;

#define G2STAGE(k0) do { \
    glds16(pA0 + (k0),      &lA[0][wave * 32][0]); \
    glds16(pA0 + (k0) + 32, &lA[1][wave * 32][0]); \
    glds16(pA1 + (k0),      &lA[0][wave * 32 + 16][0]); \
    glds16(pA1 + (k0) + 32, &lA[1][wave * 32 + 16][0]); \
    glds16(pB0 + (k0),      &lB[0][wave * 32][0]); \
    glds16(pB0 + (k0) + 32, &lB[1][wave * 32][0]); \
    glds16(pB1 + (k0),      &lB[0][wave * 32 + 16][0]); \
    glds16(pB1 + (k0) + 32, &lB[1][wave * 32 + 16][0]); \
} while (0)

    f32x4 acc[4][4];
    const f32x4 zero = {0.f, 0.f, 0.f, 0.f};
#pragma unroll
    for (int i = 0; i < 4; ++i)
#pragma unroll
        for (int j = 0; j < 4; ++j) acc[i][j] = zero;

    const int wm = (wave & 1) * 64;
    const int wn = (wave >> 1) * 64;

    const int NK = INTERI / 64;  // 8
    for (int it = 0; it < NK; ++it) {
        G2STAGE(it * 64);
        dma_barrier();
#pragma unroll
        for (int kk = 0; kk < 2; ++kk) {
            bf16x8 a[4], bv[4];
#pragma unroll
            for (int t = 0; t < 4; ++t) {
                int rr = wm + t * 16 + lrow;
                a[t] = *(const bf16x8*)&lA[kk][rr][SW(rr, quad)];
            }
#pragma unroll
            for (int t = 0; t < 4; ++t) {
                int rc = wn + t * 16 + lrow;
                bv[t] = *(const bf16x8*)&lB[kk][rc][SW(rc, quad)];
            }
#pragma unroll
            for (int i = 0; i < 4; ++i)
#pragma unroll
                for (int j = 0; j < 4; ++j)
                    acc[i][j] = __builtin_amdgcn_mfma_f32_16x16x32_bf16(a[i], bv[j], acc[i][j], 0, 0, 0);
        }
        __syncthreads();
    }
#undef G2STAGE

#pragma unroll
    for (int i = 0; i < 4; ++i) {
        int rbase = m0 + wm + i * 16 + quad * 4;
#pragma unroll
        for (int r = 0; r < 4; ++r) {
            int row = rbase + r;
            if (row >= n_e) continue;
            int tok, slot; float wt;
            if (seg == NEXP) { tok = row; slot = 4; wt = 1.f; }
            else {
                int ent = lst[seg * T_TOK + row];
                tok = ent & 0xFFFF; slot = ent >> 16;
                wt = lstw[seg * T_TOK + row];
            }
            float* prow = P + ((size_t)slot * T_TOK + tok) * DIMD + n0 + wn + lrow;
#pragma unroll
            for (int j = 0; j < 4; ++j)
                prow[j * 16] = wt * acc[i][j][r];
        }
    }
}

// ---------- combine: y = P0+P1+P2+P3+P4 ----------
__global__ __launch_bounds__(256) void combine_kernel(
    const float4* __restrict__ P, float4* __restrict__ y)
{
    const int i = blockIdx.x * 256 + threadIdx.x;   // over T*D/4
    const size_t plane = (size_t)T_TOK * DIMD / 4;
    float4 a = P[i];
    float4 b = P[plane + i];
    float4 c = P[2 * plane + i];
    float4 d = P[3 * plane + i];
    float4 e = P[4 * plane + i];
    float4 o;
    o.x = a.x + b.x + c.x + d.x + e.x;
    o.y = a.y + b.y + c.y + d.y + e.y;
    o.z = a.z + b.z + c.z + d.z + e.z;
    o.w = a.w + b.w + c.w + d.w + e.w;
    y[i] = o;
}

// ---------- launcher ----------
extern "C" void kernel_launch(void* const* d_in, const int* in_sizes, int n_in,
                              void* d_out, int out_size, void* d_ws, size_t ws_size,
                              hipStream_t stream)
{
    const float* x   = (const float*)d_in[0];
    const float* gw  = (const float*)d_in[1];
    const float* gb  = (const float*)d_in[2];
    const float* w1  = (const float*)d_in[3];
    const float* w2  = (const float*)d_in[4];
    const float* w3  = (const float*)d_in[5];
    const float* ws1 = (const float*)d_in[6];
    const float* ws2 = (const float*)d_in[7];
    const float* ws3 = (const float*)d_in[8];

    char* base = (char*)d_ws;
    size_t off = 0;
    auto alloc = [&](size_t bytes) {
        char* q = base + off; off += (bytes + 255) & ~(size_t)255; return q;
    };
    unsigned short* xb   = (unsigned short*)alloc((size_t)T_TOK * DIMD * 2);
    unsigned short* w1b  = (unsigned short*)alloc((size_t)NEXP * INTERI * DIMD * 2);
    unsigned short* w3b  = (unsigned short*)alloc((size_t)NEXP * INTERI * DIMD * 2);
    unsigned short* w2b  = (unsigned short*)alloc((size_t)NEXP * DIMD * INTERI * 2);
    unsigned short* ws1b = (unsigned short*)alloc((size_t)INTERI * DIMD * 2);
    unsigned short* ws3b = (unsigned short*)alloc((size_t)INTERI * DIMD * 2);
    unsigned short* ws2b = (unsigned short*)alloc((size_t)DIMD * INTERI * 2);
    unsigned short* Hb   = (unsigned short*)alloc((size_t)NSEG * T_TOK * INTERI * 2);
    int*            cnts = (int*)alloc(NEXP * 4);
    int*            lstp = (int*)alloc((size_t)NEXP * T_TOK * 4);
    float*          lstw = (float*)alloc((size_t)NEXP * T_TOK * 4);
    unsigned*       selp = (unsigned*)alloc((size_t)T_TOK * 4);
    float4*         selw = (float4*)alloc((size_t)T_TOK * 16);
    float*          Pb   = (float*)alloc((size_t)5 * T_TOK * DIMD * 4);

    // prep grid: 512 gate blocks FIRST, then 6528 cvt blocks (16 floats/thread)
    prep_kernel<<<7040, 256, 0, stream>>>(w1, w3, w2, ws1, ws3, ws2,
                                          w1b, w3b, w2b, ws1b, ws3b, ws2b,
                                          x, gw, gb, selp, selw, xb);
    build_lists_kernel<<<NEXP, 256, 0, stream>>>(selp, selw, cnts, lstp, lstw);
    gemm1_kernel<<<1088, 256, 0, stream>>>(xb, w1b, w3b, ws1b, ws3b, cnts, lstp, Hb);
    gemm2_kernel<<<2176, 256, 0, stream>>>(Hb, w2b, ws2b, cnts, lstp, lstw, Pb);
    combine_kernel<<<(T_TOK * DIMD / 4) / 256, 256, 0, stream>>>((const float4*)Pb, (float4*)d_out);
}